// Round 2
// baseline (1075.727 us; speedup 1.0000x reference)
//
#include <hip/hip_runtime.h>
#include <hip/hip_fp16.h>
#include <math.h>

#define N_ING 100000
#define N_DIR 50000
#define NE    1000000
#define NDST_TOTAL 300000   // 50K(cooc)+50K(used)+100K(contains)+50K(pairs)+50K(follows)
#define NBUCK 4688          // ceil(300000/64): 64 dst nodes per bucket
#define BA    16            // hist/scatter blocks per edge type
#define NBK   (5 * BA)      // 80
#define I4PT  (NE / 4)      // int4s per type
#define PB_ING 384
#define PB_DIR 192
#define LOG2E 1.442695041f

typedef float v2f __attribute__((ext_vector_type(2)));

// ============ kA: bucket histogram (LDS atomics) + fused proj+score ========
// NOTE: attention vectors are pre-scaled by log2(e) here so the aggregation
// kernel can use a bare v_exp_f32 (exp2) instead of mul+exp. leaky_relu is
// positively homogeneous and softmax is invariant to a consistent scale of
// both src and dst score halves, so this is exact up to fp rounding.
__global__ __launch_bounds__(256) void kA_kernel(
    const int* __restrict__ e0, const int* __restrict__ e1,
    const int* __restrict__ e2, const int* __restrict__ e3,
    const int* __restrict__ e4, int* __restrict__ blockcnt,
    const float* __restrict__ x_ing, const float* __restrict__ W_pi,
    const float* __restrict__ b_pi,
    const float* __restrict__ as_cooc, const float* __restrict__ as_used,
    const float* __restrict__ ad_contains,
    unsigned* __restrict__ h8_ing, __half* __restrict__ s_ing,
    const float* __restrict__ x_dir, const float* __restrict__ W_pd,
    const float* __restrict__ b_pd,
    const float* __restrict__ ad_cooc, const float* __restrict__ ad_used,
    const float* __restrict__ as_contains, const float* __restrict__ as_pairs,
    const float* __restrict__ ad_pairs, const float* __restrict__ as_follows,
    const float* __restrict__ ad_follows,
    unsigned* __restrict__ h8_dir, __half* __restrict__ s_dir)
{
    __shared__ int hist[NBUCK];
    __shared__ float sW[16 * 64];
    __shared__ float sbb[64];
    __shared__ float satt[7 * 64];
    __shared__ float sx[4][16];
    __shared__ float srow[4][64];

    const int bid = blockIdx.x;
    const int tid = threadIdx.x;
    if (bid < NBK) {
        // ---------- bucket histogram, one row per block ----------
        const int type = bid / BA, blk = bid % BA;
        const int* ei = type == 0 ? e0 : type == 1 ? e1 : type == 2 ? e2
                      : type == 3 ? e3 : e4;
        const int base = type == 0 ? 0 : type == 1 ? 50000 : type == 2 ? 100000
                       : type == 3 ? 200000 : 250000;
        for (int i = tid; i < NBUCK; i += 256) hist[i] = 0;
        __syncthreads();
        const int4* d4 = (const int4*)(ei + NE);
        for (int i = blk * 256 + tid; i < I4PT; i += BA * 256) {
            int4 d = d4[i];
            atomicAdd(&hist[(base + d.x) >> 6], 1);
            atomicAdd(&hist[(base + d.y) >> 6], 1);
            atomicAdd(&hist[(base + d.z) >> 6], 1);
            atomicAdd(&hist[(base + d.w) >> 6], 1);
        }
        __syncthreads();
        int* row = blockcnt + (size_t)bid * NBUCK;
        for (int i = tid; i < NBUCK; i += 256) row[i] = hist[i];
    } else if (bid < NBK + PB_ING) {
        // ---------- proj + fp8 pack + fp16 scores, ingredient nodes ---------
        const int g = tid >> 6, t = tid & 63;
        for (int i = tid; i < 16 * 64; i += 256) sW[i] = W_pi[i];
        if (tid < 64) {
            sbb[tid] = b_pi[tid];
            satt[tid]       = as_cooc[tid] * LOG2E;
            satt[64 + tid]  = as_used[tid] * LOG2E;
            satt[128 + tid] = ad_contains[tid] * LOG2E;
        }
        __syncthreads();
        for (int q = bid - NBK; q < N_ING / 4; q += PB_ING) {
            int n = q * 4 + g;
            if (t < 16) sx[g][t] = x_ing[(size_t)n * 16 + t];
            __syncthreads();
            float s = sbb[t];
#pragma unroll
            for (int i = 0; i < 16; ++i) s += sx[g][i] * sW[i * 64 + t];
            srow[g][t] = s;
            __syncthreads();
            if (t < 16) {
                int w0 = __builtin_amdgcn_cvt_pk_fp8_f32(srow[g][t * 4], srow[g][t * 4 + 1], 0, false);
                int w  = __builtin_amdgcn_cvt_pk_fp8_f32(srow[g][t * 4 + 2], srow[g][t * 4 + 3], w0, true);
                h8_ing[(size_t)n * 16 + t] = (unsigned)w;
            }
            if (t < 12) {
                int slot = t >> 2, hh = t & 3;
                float sc = 0.f;
#pragma unroll
                for (int d = 0; d < 16; ++d)
                    sc += srow[g][hh * 16 + d] * satt[slot * 64 + hh * 16 + d];
                s_ing[(size_t)n * 12 + t] = __float2half(sc);
            }
            __syncthreads();
        }
    } else {
        // ---------- proj + fp8 pack + fp16 scores, direction nodes ----------
        const int g = tid >> 6, t = tid & 63;
        for (int i = tid; i < 8 * 64; i += 256) sW[i] = W_pd[i];
        if (tid < 64) {
            sbb[tid] = b_pd[tid];
            satt[tid]        = ad_cooc[tid] * LOG2E;
            satt[64  + tid]  = ad_used[tid] * LOG2E;
            satt[128 + tid]  = as_contains[tid] * LOG2E;
            satt[192 + tid]  = as_pairs[tid] * LOG2E;
            satt[256 + tid]  = ad_pairs[tid] * LOG2E;
            satt[320 + tid]  = as_follows[tid] * LOG2E;
            satt[384 + tid]  = ad_follows[tid] * LOG2E;
        }
        __syncthreads();
        for (int q = bid - NBK - PB_ING; q < N_DIR / 4; q += PB_DIR) {
            int n = q * 4 + g;
            if (t < 8) sx[g][t] = x_dir[(size_t)n * 8 + t];
            __syncthreads();
            float s = sbb[t];
#pragma unroll
            for (int i = 0; i < 8; ++i) s += sx[g][i] * sW[i * 64 + t];
            srow[g][t] = s;
            __syncthreads();
            if (t < 16) {
                int w0 = __builtin_amdgcn_cvt_pk_fp8_f32(srow[g][t * 4], srow[g][t * 4 + 1], 0, false);
                int w  = __builtin_amdgcn_cvt_pk_fp8_f32(srow[g][t * 4 + 2], srow[g][t * 4 + 3], w0, true);
                h8_dir[(size_t)n * 16 + t] = (unsigned)w;
            }
            if (t < 28) {
                int slot = t >> 2, hh = t & 3;
                float sc = 0.f;
#pragma unroll
                for (int d = 0; d < 16; ++d)
                    sc += srow[g][hh * 16 + d] * satt[slot * 64 + hh * 16 + d];
                s_dir[(size_t)n * 28 + t] = __float2half(sc);
            }
            __syncthreads();
        }
    }
}

// ============ k2: bucket totals + bases, 64 buckets x 4 threads per block ==
__global__ __launch_bounds__(256) void k2_kernel(
    const int* __restrict__ blockcnt, int* __restrict__ blockbase,
    int* __restrict__ bbase, int* __restrict__ btot, int* __restrict__ cursor)
{
    __shared__ int part[4][64];
    __shared__ int tots[64];
    __shared__ int scn[64];
    __shared__ int bw;
    const int tid = threadIdx.x;
    const int kq = tid >> 6, bl = tid & 63;   // 4 k-quarters x 64 buckets
    const int b = blockIdx.x * 64 + bl;
    const int K = NBK / 4;                    // 20 rows per quarter
    int ps = 0;
    if (b < NBUCK)
        for (int k = kq * K; k < kq * K + K; ++k)
            ps += blockcnt[(size_t)k * NBUCK + b];
    part[kq][bl] = ps;
    __syncthreads();
    if (tid < 64) {
        int t = part[0][tid] + part[1][tid] + part[2][tid] + part[3][tid];
        tots[tid] = t;
        scn[tid] = t;
    }
    __syncthreads();
    for (int off = 1; off < 64; off <<= 1) {
        int v = 0;
        if (tid < 64 && tid >= off) v = scn[tid - off];
        __syncthreads();
        if (tid < 64) scn[tid] += v;
        __syncthreads();
    }
    if (tid == 63) bw = atomicAdd(cursor, scn[63]);
    __syncthreads();
    if (b < NBUCK) {
        int bs = bw + scn[bl] - tots[bl];     // exclusive bucket base
        if (kq == 0) {
            bbase[b] = bs;
            btot[b] = tots[bl];
        }
        int run = bs;
        for (int q = 0; q < kq; ++q) run += part[q][bl];
        for (int k = kq * K; k < kq * K + K; ++k) {
            blockbase[(size_t)k * NBUCK + b] = run;
            run += blockcnt[(size_t)k * NBUCK + b];
        }
    }
}

// ============ k3: bucket scatter (LDS cursors, packed u32 entries) =========
__global__ __launch_bounds__(256) void k3_kernel(
    const int* __restrict__ e0, const int* __restrict__ e1,
    const int* __restrict__ e2, const int* __restrict__ e3,
    const int* __restrict__ e4, const int* __restrict__ blockbase,
    unsigned* __restrict__ bpair)
{
    __shared__ int cur[NBUCK];
    const int bid = blockIdx.x, tid = threadIdx.x;
    const int type = bid / BA, blk = bid % BA;
    const int* ei = type == 0 ? e0 : type == 1 ? e1 : type == 2 ? e2
                  : type == 3 ? e3 : e4;
    const int base = type == 0 ? 0 : type == 1 ? 50000 : type == 2 ? 100000
                   : type == 3 ? 200000 : 250000;
    const int* row = blockbase + (size_t)bid * NBUCK;
    for (int i = tid; i < NBUCK; i += 256) cur[i] = row[i];
    __syncthreads();
    const int4* s4 = (const int4*)ei;
    const int4* d4 = (const int4*)(ei + NE);
    for (int i = blk * 256 + tid; i < I4PT; i += BA * 256) {
        int4 s = s4[i];
        int4 d = d4[i];
        int g0 = base + d.x, g1 = base + d.y, g2 = base + d.z, g3 = base + d.w;
        int p0 = atomicAdd(&cur[g0 >> 6], 1);
        int p1 = atomicAdd(&cur[g1 >> 6], 1);
        int p2 = atomicAdd(&cur[g2 >> 6], 1);
        int p3 = atomicAdd(&cur[g3 >> 6], 1);
        bpair[p0] = ((unsigned)(g0 & 63) << 17) | (unsigned)s.x;
        bpair[p1] = ((unsigned)(g1 & 63) << 17) | (unsigned)s.y;
        bpair[p2] = ((unsigned)(g2 & 63) << 17) | (unsigned)s.z;
        bpair[p3] = ((unsigned)(g3 & 63) << 17) | (unsigned)s.w;
    }
}

// ============ k4: per-bucket counting sort -> perm + start/cnt =============
__global__ __launch_bounds__(256) void k4_kernel(
    const unsigned* __restrict__ bpair, const int* __restrict__ bbase,
    const int* __restrict__ btot, int* __restrict__ perm,
    int* __restrict__ start, int* __restrict__ cnt)
{
    __shared__ int h[64], sc[64], cu[64];
    const int b = blockIdx.x, tid = threadIdx.x;
    const int jb = bbase[b], n = btot[b];
    if (tid < 64) h[tid] = 0;
    __syncthreads();
    for (int i = tid; i < n; i += 256)
        atomicAdd(&h[bpair[jb + i] >> 17], 1);
    __syncthreads();
    if (tid == 0) {
        int r = 0;
        for (int i = 0; i < 64; ++i) { sc[i] = r; cu[i] = r; r += h[i]; }
    }
    __syncthreads();
    if (tid < 64) {
        int dg = b * 64 + tid;
        if (dg < NDST_TOTAL) {
            start[dg] = jb + sc[tid];
            cnt[dg] = h[tid];
        }
    }
    for (int i = tid; i < n; i += 256) {
        unsigned p = bpair[jb + i];
        int pos = atomicAdd(&cu[p >> 17], 1);
        perm[jb + pos] = (int)(p & 0x1FFFF);
    }
}

// ============ fused aggregation: fp8 rows, fp16 scores, 8 edges/iter =======
// Each wave processes a ROUND of 4 consecutive dsts (type boundaries are all
// multiples of 4, so a round never spans types). The 4 normalized rows are
// buffered in LDS, then one 4-row batched matvec amortizes each WkT b128
// read across 4 FMAs: matvec LDS traffic drops from ~16KB to 4KB per dst.
// WkT is staged transposed+padded [64][68] (272B rows: 16B-aligned, banks
// spread (4t+k)%32) so per-lane reads are conflict-free ds_read_b128.
__global__ __launch_bounds__(256) void agg_all_kernel(
    const int* __restrict__ perm, const int* __restrict__ start,
    const int* __restrict__ cnttot,
    const unsigned* __restrict__ h8_ing, const unsigned* __restrict__ h8_dir,
    const __half* __restrict__ s_ing, const __half* __restrict__ s_dir,
    const float* __restrict__ Wk, const float* __restrict__ bk,
    float* __restrict__ pool_ing, float* __restrict__ pool_dir,
    float* __restrict__ sem_dir)
{
    __shared__ __align__(16) float sWkT[64 * 68];    // transposed, padded
    __shared__ __align__(16) float srow4[4][4][64];  // [wave][row][feat]
    __shared__ float sred[4][64];
    const int t = threadIdx.x & 63, w = threadIdx.x >> 6;
    const int g  = t >> 4;       // edge group 0..3
    const int l4 = t & 15;       // feature quad: 4*l4 .. 4*l4+3
    const int hq = l4 >> 2;      // head of my features

    // stage WkT[t][k] = Wk[k*64+t] (coalesced global reads)
    for (int i = threadIdx.x; i < 4096; i += 256)
        sWkT[(i & 63) * 68 + (i >> 6)] = Wk[i];
    const float bkf = bk[t];

    float p_ing = 0.f;
    float p0 = 0.f, p1 = 0.f, p2 = 0.f, p3 = 0.f;
    float m0 = 0.f, m1 = 0.f, m2 = 0.f, m3 = 0.f;
    __syncthreads();
    const int nwaves = gridDim.x * 4;
    const int NR = NDST_TOTAL / 4;   // 75000 rounds of 4 consecutive dsts
    for (int r = blockIdx.x * 4 + w; r < NR; r += nwaves) {
        const int d0 = r * 4;
        int type, ldb;
        const __half *ssrc, *sdst;
        const unsigned* hsrc;
        unsigned uss, uds; int soff, doff;
        if (d0 < 50000)       { type = 0; ldb = d0;          ssrc = s_ing; uss = 12; soff = 0;  sdst = s_dir; uds = 28; doff = 0;  hsrc = h8_ing; }
        else if (d0 < 100000) { type = 1; ldb = d0 - 50000;  ssrc = s_ing; uss = 12; soff = 4;  sdst = s_dir; uds = 28; doff = 4;  hsrc = h8_ing; }
        else if (d0 < 200000) { type = 2; ldb = d0 - 100000; ssrc = s_dir; uss = 28; soff = 8;  sdst = s_ing; uds = 12; doff = 8;  hsrc = h8_dir; }
        else if (d0 < 250000) { type = 3; ldb = d0 - 200000; ssrc = s_dir; uss = 28; soff = 12; sdst = s_dir; uds = 28; doff = 16; hsrc = h8_dir; }
        else                  { type = 4; ldb = d0 - 250000; ssrc = s_dir; uss = 28; soff = 20; sdst = s_dir; uds = 28; doff = 24; hsrc = h8_dir; }
        const unsigned usoff = (unsigned)(soff + hq);

        // ---- 4 per-dst edge aggregations ----
        for (int rr = 0; rr < 4; ++rr) {
            const int d = d0 + rr;
            float adst = __half2float(sdst[(unsigned)(ldb + rr) * uds + (unsigned)(doff + hq)]);
            int jb = start[d], je = jb + cnttot[d];
            float4 acc = make_float4(0.f, 0.f, 0.f, 0.f);
            float dsum = 0.f;
            for (int j = jb; j < je; j += 8) {
                int j0 = j + g, j1 = j + 4 + g;
                bool v0 = j0 < je, v1 = j1 < je;
                unsigned s0 = (unsigned)perm[v0 ? j0 : je - 1];
                unsigned s1 = (unsigned)perm[v1 ? j1 : je - 1];
                float c0 = __half2float(ssrc[s0 * uss + usoff]);
                float c1 = __half2float(ssrc[s1 * uss + usoff]);
                unsigned u0 = hsrc[s0 * 16u + (unsigned)l4];
                unsigned u1 = hsrc[s1 * 16u + (unsigned)l4];
                float a0 = c0 + adst; a0 = a0 > 0.f ? a0 : 0.2f * a0;
                float a1 = c1 + adst; a1 = a1 > 0.f ? a1 : 0.2f * a1;
                float e0 = v0 ? __builtin_amdgcn_exp2f(a0) : 0.f;  // scores pre-scaled by log2e
                float e1 = v1 ? __builtin_amdgcn_exp2f(a1) : 0.f;
                dsum += e0 + e1;
                v2f lo0 = __builtin_amdgcn_cvt_pk_f32_fp8((int)u0, false);
                v2f hi0 = __builtin_amdgcn_cvt_pk_f32_fp8((int)u0, true);
                v2f lo1 = __builtin_amdgcn_cvt_pk_f32_fp8((int)u1, false);
                v2f hi1 = __builtin_amdgcn_cvt_pk_f32_fp8((int)u1, true);
                acc.x += lo0.x * e0 + lo1.x * e1;
                acc.y += lo0.y * e0 + lo1.y * e1;
                acc.z += hi0.x * e0 + hi1.x * e1;
                acc.w += hi0.y * e0 + hi1.y * e1;
            }
#pragma unroll
            for (int mask = 16; mask <= 32; mask <<= 1) {
                acc.x += __shfl_xor(acc.x, mask, 64);
                acc.y += __shfl_xor(acc.y, mask, 64);
                acc.z += __shfl_xor(acc.z, mask, 64);
                acc.w += __shfl_xor(acc.w, mask, 64);
                dsum  += __shfl_xor(dsum,  mask, 64);
            }
            float inv = 1.f / (dsum + 1e-16f);
            float4 v4 = make_float4(fmaxf(acc.x * inv, 0.f), fmaxf(acc.y * inv, 0.f),
                                    fmaxf(acc.z * inv, 0.f), fmaxf(acc.w * inv, 0.f));
            if (g == 0) *(float4*)&srow4[w][rr][l4 * 4] = v4;  // rebroadcast layout
        }

        // ---- per-round pooling + 4-row batched semantic matvec ----
        float v0 = srow4[w][0][t], v1 = srow4[w][1][t];
        float v2 = srow4[w][2][t], v3 = srow4[w][3][t];
        float vsum = v0 + v1 + v2 + v3;
        if (type == 2) {
            p_ing += vsum;
        } else {
            float a0 = bkf, a1 = bkf, a2 = bkf, a3 = bkf;
#pragma unroll
            for (int kq = 0; kq < 16; ++kq) {
                float4 wq = *(const float4*)&sWkT[t * 68 + kq * 4];  // per-lane b128
                float4 r0 = *(const float4*)&srow4[w][0][kq * 4];    // broadcast b128
                float4 r1 = *(const float4*)&srow4[w][1][kq * 4];
                float4 r2 = *(const float4*)&srow4[w][2][kq * 4];
                float4 r3 = *(const float4*)&srow4[w][3][kq * 4];
                a0 += r0.x * wq.x + r0.y * wq.y + r0.z * wq.z + r0.w * wq.w;
                a1 += r1.x * wq.x + r1.y * wq.y + r1.z * wq.z + r1.w * wq.w;
                a2 += r2.x * wq.x + r2.y * wq.y + r2.z * wq.z + r2.w * wq.w;
                a3 += r3.x * wq.x + r3.y * wq.y + r3.z * wq.z + r3.w * wq.w;
            }
            float tsum = tanhf(a0) + tanhf(a1) + tanhf(a2) + tanhf(a3);
            if (type == 0)      { p0 += vsum; m0 += tsum; }
            else if (type == 1) { p1 += vsum; m1 += tsum; }
            else if (type == 3) { p2 += vsum; m2 += tsum; }
            else                { p3 += vsum; m3 += tsum; }
        }
    }
    float vals[9] = { p_ing, p0, p1, p2, p3, m0, m1, m2, m3 };
    float* outs[9] = { pool_ing, pool_dir, pool_dir + 64, pool_dir + 128,
                       pool_dir + 192, sem_dir, sem_dir + 64, sem_dir + 128,
                       sem_dir + 192 };
    for (int i = 0; i < 9; ++i) {
        __syncthreads();
        sred[w][t] = vals[i];
        __syncthreads();
        if (w == 0)
            atomicAdd(&outs[i][t], sred[0][t] + sred[1][t] + sred[2][t] + sred[3][t]);
    }
}

// ============ final: semantic softmax + pools + VAE head ===================
__global__ __launch_bounds__(64) void final_kernel(
    const float* __restrict__ pool_ing, const float* __restrict__ pool_dir,
    const float* __restrict__ sem_dir, const float* __restrict__ q,
    const float* __restrict__ cond, const float* __restrict__ eps,
    const float* __restrict__ W_mu, const float* __restrict__ b_mu,
    const float* __restrict__ W_lv, const float* __restrict__ b_lv,
    const float* __restrict__ W_fc3, const float* __restrict__ b_fc3,
    const float* __restrict__ W_fc2, const float* __restrict__ b_fc2,
    float* __restrict__ out)
{
    __shared__ float gr[136];
    __shared__ float sc[4], attn[4];
    __shared__ float z[32], hfc[64];
    int t = threadIdx.x;  // 64 threads
    if (t < 4) {
        float s = 0.f;
        for (int f = 0; f < 64; ++f)
            s += (sem_dir[t * 64 + f] / (float)N_DIR) * q[f];
        sc[t] = s;
    }
    gr[t] = pool_ing[t] / (float)N_ING;   // out_ing == o_cont (T=1 softmax)
    __syncthreads();
    if (t == 0) {
        float m = fmaxf(fmaxf(sc[0], sc[1]), fmaxf(sc[2], sc[3]));
        float ssum = 0.f;
        for (int i = 0; i < 4; ++i) { attn[i] = expf(sc[i] - m); ssum += attn[i]; }
        for (int i = 0; i < 4; ++i) attn[i] /= ssum;
    }
    __syncthreads();
    {
        float v = 0.f;
        for (int tt = 0; tt < 4; ++tt)
            v += attn[tt] * (pool_dir[tt * 64 + t] / (float)N_DIR);
        gr[64 + t] = v;
    }
    if (t < 8) gr[128 + t] = cond[t];
    __syncthreads();
    if (t < 32) {
        float m = b_mu[t], lv = b_lv[t];
        for (int i = 0; i < 136; ++i) {
            float g = gr[i];
            m  += g * W_mu[i * 32 + t];
            lv += g * W_lv[i * 32 + t];
        }
        out[16 + t] = m;
        out[48 + t] = lv;
        z[t] = m + eps[t] * expf(0.5f * lv);
    }
    __syncthreads();
    {
        float v = b_fc3[t];
        for (int j = 0; j < 32; ++j) v += z[j] * W_fc3[j * 64 + t];
        hfc[t] = fmaxf(v, 0.f);
    }
    __syncthreads();
    if (t < 16) {
        float v = b_fc2[t];
        for (int f = 0; f < 64; ++f) v += hfc[f] * W_fc2[f * 16 + t];
        out[t] = tanhf(v);
    }
}

extern "C" void kernel_launch(void* const* d_in, const int* in_sizes, int n_in,
                              void* d_out, int out_size, void* d_ws, size_t ws_size,
                              hipStream_t stream) {
    const float* x_ing = (const float*)d_in[0];
    const float* x_dir = (const float*)d_in[1];
    const float* cond  = (const float*)d_in[2];
    const float* eps   = (const float*)d_in[3];
    const int* ei_cooc     = (const int*)d_in[4];
    const int* ei_used     = (const int*)d_in[5];
    const int* ei_contains = (const int*)d_in[6];
    const int* ei_pairs    = (const int*)d_in[7];
    const int* ei_follows  = (const int*)d_in[8];
    const float* W_pi = (const float*)d_in[9];
    const float* b_pi = (const float*)d_in[10];
    const float* W_pd = (const float*)d_in[11];
    const float* b_pd = (const float*)d_in[12];
    const float* Wk   = (const float*)d_in[13];
    const float* bk   = (const float*)d_in[14];
    const float* q    = (const float*)d_in[15];
    const float* W_mu = (const float*)d_in[16];
    const float* b_mu = (const float*)d_in[17];
    const float* W_lv = (const float*)d_in[18];
    const float* b_lv = (const float*)d_in[19];
    const float* W_fc3 = (const float*)d_in[20];
    const float* b_fc3 = (const float*)d_in[21];
    const float* W_fc2 = (const float*)d_in[22];
    const float* b_fc2 = (const float*)d_in[23];
    const float* as_cooc     = (const float*)d_in[24];
    const float* ad_cooc     = (const float*)d_in[25];
    const float* as_used     = (const float*)d_in[26];
    const float* ad_used     = (const float*)d_in[27];
    const float* as_contains = (const float*)d_in[28];
    const float* ad_contains = (const float*)d_in[29];
    const float* as_pairs    = (const float*)d_in[30];
    const float* ad_pairs    = (const float*)d_in[31];
    const float* as_follows  = (const float*)d_in[32];
    const float* ad_follows  = (const float*)d_in[33];

    // ---- workspace layout ----
    unsigned* bpair = (unsigned*)d_ws;                        // 5M u32 (20 MB)
    unsigned* h8_ing = bpair + (size_t)5 * NE;                // N_ING*16 u32
    unsigned* h8_dir = h8_ing + (size_t)N_ING * 16;           // N_DIR*16
    __half* s_ing = (__half*)(h8_dir + (size_t)N_DIR * 16);   // N_ING*12 fp16
    __half* s_dir = s_ing + (size_t)N_ING * 12;               // N_DIR*28 fp16
    int*   perm  = (int*)(s_dir + (size_t)N_DIR * 28);        // 5M
    int*   blockcnt  = perm + (size_t)5 * NE;                 // 80*4688
    int*   blockbase = blockcnt + (size_t)NBK * NBUCK;        // 80*4688
    int*   bbase  = blockbase + (size_t)NBK * NBUCK;          // 4688
    int*   btot   = bbase + NBUCK;                            // 4688
    int*   start  = btot + NBUCK;                             // 300K
    int*   cnt    = start + NDST_TOTAL;                       // 300K
    int*   cursor = cnt + NDST_TOTAL;                         // 1  (zeroed region)
    float* pool_ing = (float*)(cursor + 1);                   // 64
    float* pool_dir = pool_ing + 64;                          // 4*64
    float* sem_dir  = pool_dir + 256;                         // 4*64

    // tiny memset: cursor + pools
    hipMemsetAsync(cursor, 0, (1 + 64 + 256 + 256) * sizeof(int), stream);

    // kA: bucket histogram (LDS-only atomics) + fused proj/fp8/fp16-score
    kA_kernel<<<NBK + PB_ING + PB_DIR, 256, 0, stream>>>(
        ei_cooc, ei_used, ei_contains, ei_pairs, ei_follows, blockcnt,
        x_ing, W_pi, b_pi, as_cooc, as_used, ad_contains, h8_ing, s_ing,
        x_dir, W_pd, b_pd, ad_cooc, ad_used, as_contains, as_pairs, ad_pairs,
        as_follows, ad_follows, h8_dir, s_dir);

    // k2: bucket scan -> bases (64 buckets x 4 threads per block)
    k2_kernel<<<(NBUCK + 63) / 64, 256, 0, stream>>>(
        blockcnt, blockbase, bbase, btot, cursor);

    // k3: bucket scatter (LDS cursors, u32 packed)
    k3_kernel<<<NBK, 256, 0, stream>>>(
        ei_cooc, ei_used, ei_contains, ei_pairs, ei_follows, blockbase, bpair);

    // k4: per-bucket counting sort -> perm + start/cnt
    k4_kernel<<<NBUCK, 256, 0, stream>>>(bpair, bbase, btot, perm, start, cnt);

    // agg over all 300K dst segments (75K rounds of 4)
    agg_all_kernel<<<2048, 256, 0, stream>>>(
        perm, start, cnt, h8_ing, h8_dir, s_ing, s_dir, Wk, bk,
        pool_ing, pool_dir, sem_dir);

    final_kernel<<<1, 64, 0, stream>>>(
        pool_ing, pool_dir, sem_dir, q, cond, eps,
        W_mu, b_mu, W_lv, b_lv, W_fc3, b_fc3, W_fc2, b_fc2, (float*)d_out);
}

// Round 3
// 593.864 us; speedup vs baseline: 1.8114x; 1.8114x over previous
//
#include <hip/hip_runtime.h>
#include <hip/hip_fp16.h>
#include <math.h>

#define N_ING 100000
#define N_DIR 50000
#define NE    1000000
#define NDST_TOTAL 300000   // 50K(cooc)+50K(used)+100K(contains)+50K(pairs)+50K(follows)
#define NBUCK 4688          // ceil(300000/64): 64 dst nodes per bucket
#define BA    16            // hist/scatter blocks per edge type
#define NBK   (5 * BA)      // 80
#define I4PT  (NE / 4)      // int4s per type
#define PB_ING 384
#define PB_DIR 192
#define LOG2E 1.442695041f

typedef float v2f __attribute__((ext_vector_type(2)));

// ============ kA: bucket histogram (LDS atomics) + fused proj+score ========
// Attention vectors pre-scaled by log2(e) so agg uses bare v_exp_f32 (exp2).
__global__ __launch_bounds__(256) void kA_kernel(
    const int* __restrict__ e0, const int* __restrict__ e1,
    const int* __restrict__ e2, const int* __restrict__ e3,
    const int* __restrict__ e4, int* __restrict__ blockcnt,
    const float* __restrict__ x_ing, const float* __restrict__ W_pi,
    const float* __restrict__ b_pi,
    const float* __restrict__ as_cooc, const float* __restrict__ as_used,
    const float* __restrict__ ad_contains,
    unsigned* __restrict__ h8_ing, __half* __restrict__ s_ing,
    const float* __restrict__ x_dir, const float* __restrict__ W_pd,
    const float* __restrict__ b_pd,
    const float* __restrict__ ad_cooc, const float* __restrict__ ad_used,
    const float* __restrict__ as_contains, const float* __restrict__ as_pairs,
    const float* __restrict__ ad_pairs, const float* __restrict__ as_follows,
    const float* __restrict__ ad_follows,
    unsigned* __restrict__ h8_dir, __half* __restrict__ s_dir)
{
    __shared__ int hist[NBUCK];
    __shared__ float sW[16 * 64];
    __shared__ float sbb[64];
    __shared__ float satt[7 * 64];
    __shared__ float sx[4][16];
    __shared__ float srow[4][64];

    const int bid = blockIdx.x;
    const int tid = threadIdx.x;
    if (bid < NBK) {
        // ---------- bucket histogram, one row per block ----------
        const int type = bid / BA, blk = bid % BA;
        const int* ei = type == 0 ? e0 : type == 1 ? e1 : type == 2 ? e2
                      : type == 3 ? e3 : e4;
        const int base = type == 0 ? 0 : type == 1 ? 50000 : type == 2 ? 100000
                       : type == 3 ? 200000 : 250000;
        for (int i = tid; i < NBUCK; i += 256) hist[i] = 0;
        __syncthreads();
        const int4* d4 = (const int4*)(ei + NE);
        for (int i = blk * 256 + tid; i < I4PT; i += BA * 256) {
            int4 d = d4[i];
            atomicAdd(&hist[(base + d.x) >> 6], 1);
            atomicAdd(&hist[(base + d.y) >> 6], 1);
            atomicAdd(&hist[(base + d.z) >> 6], 1);
            atomicAdd(&hist[(base + d.w) >> 6], 1);
        }
        __syncthreads();
        int* row = blockcnt + (size_t)bid * NBUCK;
        for (int i = tid; i < NBUCK; i += 256) row[i] = hist[i];
    } else if (bid < NBK + PB_ING) {
        // ---------- proj + fp8 pack + fp16 scores, ingredient nodes ---------
        const int g = tid >> 6, t = tid & 63;
        for (int i = tid; i < 16 * 64; i += 256) sW[i] = W_pi[i];
        if (tid < 64) {
            sbb[tid] = b_pi[tid];
            satt[tid]       = as_cooc[tid] * LOG2E;
            satt[64 + tid]  = as_used[tid] * LOG2E;
            satt[128 + tid] = ad_contains[tid] * LOG2E;
        }
        __syncthreads();
        for (int q = bid - NBK; q < N_ING / 4; q += PB_ING) {
            int n = q * 4 + g;
            if (t < 16) sx[g][t] = x_ing[(size_t)n * 16 + t];
            __syncthreads();
            float s = sbb[t];
#pragma unroll
            for (int i = 0; i < 16; ++i) s += sx[g][i] * sW[i * 64 + t];
            srow[g][t] = s;
            __syncthreads();
            if (t < 16) {
                int w0 = __builtin_amdgcn_cvt_pk_fp8_f32(srow[g][t * 4], srow[g][t * 4 + 1], 0, false);
                int w  = __builtin_amdgcn_cvt_pk_fp8_f32(srow[g][t * 4 + 2], srow[g][t * 4 + 3], w0, true);
                h8_ing[(size_t)n * 16 + t] = (unsigned)w;
            }
            if (t < 12) {
                int slot = t >> 2, hh = t & 3;
                float sc = 0.f;
#pragma unroll
                for (int d = 0; d < 16; ++d)
                    sc += srow[g][hh * 16 + d] * satt[slot * 64 + hh * 16 + d];
                s_ing[(size_t)n * 12 + t] = __float2half(sc);
            }
            __syncthreads();
        }
    } else {
        // ---------- proj + fp8 pack + fp16 scores, direction nodes ----------
        const int g = tid >> 6, t = tid & 63;
        for (int i = tid; i < 8 * 64; i += 256) sW[i] = W_pd[i];
        if (tid < 64) {
            sbb[tid] = b_pd[tid];
            satt[tid]        = ad_cooc[tid] * LOG2E;
            satt[64  + tid]  = ad_used[tid] * LOG2E;
            satt[128 + tid]  = as_contains[tid] * LOG2E;
            satt[192 + tid]  = as_pairs[tid] * LOG2E;
            satt[256 + tid]  = ad_pairs[tid] * LOG2E;
            satt[320 + tid]  = as_follows[tid] * LOG2E;
            satt[384 + tid]  = ad_follows[tid] * LOG2E;
        }
        __syncthreads();
        for (int q = bid - NBK - PB_ING; q < N_DIR / 4; q += PB_DIR) {
            int n = q * 4 + g;
            if (t < 8) sx[g][t] = x_dir[(size_t)n * 8 + t];
            __syncthreads();
            float s = sbb[t];
#pragma unroll
            for (int i = 0; i < 8; ++i) s += sx[g][i] * sW[i * 64 + t];
            srow[g][t] = s;
            __syncthreads();
            if (t < 16) {
                int w0 = __builtin_amdgcn_cvt_pk_fp8_f32(srow[g][t * 4], srow[g][t * 4 + 1], 0, false);
                int w  = __builtin_amdgcn_cvt_pk_fp8_f32(srow[g][t * 4 + 2], srow[g][t * 4 + 3], w0, true);
                h8_dir[(size_t)n * 16 + t] = (unsigned)w;
            }
            if (t < 28) {
                int slot = t >> 2, hh = t & 3;
                float sc = 0.f;
#pragma unroll
                for (int d = 0; d < 16; ++d)
                    sc += srow[g][hh * 16 + d] * satt[slot * 64 + hh * 16 + d];
                s_dir[(size_t)n * 28 + t] = __float2half(sc);
            }
            __syncthreads();
        }
    }
}

// ============ k2: bucket totals + bases, 64 buckets x 4 threads per block ==
__global__ __launch_bounds__(256) void k2_kernel(
    const int* __restrict__ blockcnt, int* __restrict__ blockbase,
    int* __restrict__ bbase, int* __restrict__ btot, int* __restrict__ cursor)
{
    __shared__ int part[4][64];
    __shared__ int tots[64];
    __shared__ int scn[64];
    __shared__ int bw;
    const int tid = threadIdx.x;
    const int kq = tid >> 6, bl = tid & 63;   // 4 k-quarters x 64 buckets
    const int b = blockIdx.x * 64 + bl;
    const int K = NBK / 4;                    // 20 rows per quarter
    int ps = 0;
    if (b < NBUCK)
        for (int k = kq * K; k < kq * K + K; ++k)
            ps += blockcnt[(size_t)k * NBUCK + b];
    part[kq][bl] = ps;
    __syncthreads();
    if (tid < 64) {
        int t = part[0][tid] + part[1][tid] + part[2][tid] + part[3][tid];
        tots[tid] = t;
        scn[tid] = t;
    }
    __syncthreads();
    for (int off = 1; off < 64; off <<= 1) {
        int v = 0;
        if (tid < 64 && tid >= off) v = scn[tid - off];
        __syncthreads();
        if (tid < 64) scn[tid] += v;
        __syncthreads();
    }
    if (tid == 63) bw = atomicAdd(cursor, scn[63]);
    __syncthreads();
    if (b < NBUCK) {
        int bs = bw + scn[bl] - tots[bl];     // exclusive bucket base
        if (kq == 0) {
            bbase[b] = bs;
            btot[b] = tots[bl];
        }
        int run = bs;
        for (int q = 0; q < kq; ++q) run += part[q][bl];
        for (int k = kq * K; k < kq * K + K; ++k) {
            blockbase[(size_t)k * NBUCK + b] = run;
            run += blockcnt[(size_t)k * NBUCK + b];
        }
    }
}

// ============ k3: bucket scatter (LDS cursors, packed u32 entries) =========
__global__ __launch_bounds__(256) void k3_kernel(
    const int* __restrict__ e0, const int* __restrict__ e1,
    const int* __restrict__ e2, const int* __restrict__ e3,
    const int* __restrict__ e4, const int* __restrict__ blockbase,
    unsigned* __restrict__ bpair)
{
    __shared__ int cur[NBUCK];
    const int bid = blockIdx.x, tid = threadIdx.x;
    const int type = bid / BA, blk = bid % BA;
    const int* ei = type == 0 ? e0 : type == 1 ? e1 : type == 2 ? e2
                  : type == 3 ? e3 : e4;
    const int base = type == 0 ? 0 : type == 1 ? 50000 : type == 2 ? 100000
                   : type == 3 ? 200000 : 250000;
    const int* row = blockbase + (size_t)bid * NBUCK;
    for (int i = tid; i < NBUCK; i += 256) cur[i] = row[i];
    __syncthreads();
    const int4* s4 = (const int4*)ei;
    const int4* d4 = (const int4*)(ei + NE);
    for (int i = blk * 256 + tid; i < I4PT; i += BA * 256) {
        int4 s = s4[i];
        int4 d = d4[i];
        int g0 = base + d.x, g1 = base + d.y, g2 = base + d.z, g3 = base + d.w;
        int p0 = atomicAdd(&cur[g0 >> 6], 1);
        int p1 = atomicAdd(&cur[g1 >> 6], 1);
        int p2 = atomicAdd(&cur[g2 >> 6], 1);
        int p3 = atomicAdd(&cur[g3 >> 6], 1);
        bpair[p0] = ((unsigned)(g0 & 63) << 17) | (unsigned)s.x;
        bpair[p1] = ((unsigned)(g1 & 63) << 17) | (unsigned)s.y;
        bpair[p2] = ((unsigned)(g2 & 63) << 17) | (unsigned)s.z;
        bpair[p3] = ((unsigned)(g3 & 63) << 17) | (unsigned)s.w;
    }
}

// ============ k4: per-bucket counting sort -> perm + start/cnt =============
__global__ __launch_bounds__(256) void k4_kernel(
    const unsigned* __restrict__ bpair, const int* __restrict__ bbase,
    const int* __restrict__ btot, int* __restrict__ perm,
    int* __restrict__ start, int* __restrict__ cnt)
{
    __shared__ int h[64], sc[64], cu[64];
    const int b = blockIdx.x, tid = threadIdx.x;
    const int jb = bbase[b], n = btot[b];
    if (tid < 64) h[tid] = 0;
    __syncthreads();
    for (int i = tid; i < n; i += 256)
        atomicAdd(&h[bpair[jb + i] >> 17], 1);
    __syncthreads();
    if (tid == 0) {
        int r = 0;
        for (int i = 0; i < 64; ++i) { sc[i] = r; cu[i] = r; r += h[i]; }
    }
    __syncthreads();
    if (tid < 64) {
        int dg = b * 64 + tid;
        if (dg < NDST_TOTAL) {
            start[dg] = jb + sc[tid];
            cnt[dg] = h[tid];
        }
    }
    for (int i = tid; i < n; i += 256) {
        unsigned p = bpair[jb + i];
        int pos = atomicAdd(&cu[p >> 17], 1);
        perm[jb + pos] = (int)(p & 0x1FFFF);
    }
}

// ============ fused aggregation: fp8 rows, fp16 scores, 8 edges/iter =======
// R0 structure (VGPR ~32-36, occupancy-protected). Semantic matvec + tanh
// OFFLOADED: non-contains rows are written as fp8 (16 u32/dst) into the
// dead bpair buffer; sem_kernel consumes them. Pools stay in f32 here.
__global__ __launch_bounds__(256) void agg_all_kernel(
    const int* __restrict__ perm, const int* __restrict__ start,
    const int* __restrict__ cnttot,
    const unsigned* __restrict__ h8_ing, const unsigned* __restrict__ h8_dir,
    const __half* __restrict__ s_ing, const __half* __restrict__ s_dir,
    unsigned* __restrict__ rows8,
    float* __restrict__ pool_ing, float* __restrict__ pool_dir)
{
    __shared__ __align__(16) float srow[4][64];
    __shared__ float sred[4][64];
    const int t = threadIdx.x & 63, w = threadIdx.x >> 6;
    const int g  = t >> 4;       // edge group 0..3
    const int l4 = t & 15;       // feature quad: 4*l4 .. 4*l4+3
    const int hq = l4 >> 2;      // head of my features

    float p_ing = 0.f;
    float p0 = 0.f, p1 = 0.f, p2 = 0.f, p3 = 0.f;
    const int nwaves = gridDim.x * 4;
    for (int d = blockIdx.x * 4 + w; d < NDST_TOTAL; d += nwaves) {
        int type, ld;
        const __half *ssrc, *sdst;
        const unsigned* hsrc;
        unsigned uss, uds; int soff, doff;
        if (d < 50000)       { type = 0; ld = d;          ssrc = s_ing; uss = 12; soff = 0;  sdst = s_dir; uds = 28; doff = 0;  hsrc = h8_ing; }
        else if (d < 100000) { type = 1; ld = d - 50000;  ssrc = s_ing; uss = 12; soff = 4;  sdst = s_dir; uds = 28; doff = 4;  hsrc = h8_ing; }
        else if (d < 200000) { type = 2; ld = d - 100000; ssrc = s_dir; uss = 28; soff = 8;  sdst = s_ing; uds = 12; doff = 8;  hsrc = h8_dir; }
        else if (d < 250000) { type = 3; ld = d - 200000; ssrc = s_dir; uss = 28; soff = 12; sdst = s_dir; uds = 28; doff = 16; hsrc = h8_dir; }
        else                 { type = 4; ld = d - 250000; ssrc = s_dir; uss = 28; soff = 20; sdst = s_dir; uds = 28; doff = 24; hsrc = h8_dir; }
        float adst = __half2float(sdst[(unsigned)ld * uds + (unsigned)(doff + hq)]);
        const unsigned usoff = (unsigned)(soff + hq);
        int jb = start[d], je = jb + cnttot[d];
        float4 acc = make_float4(0.f, 0.f, 0.f, 0.f);
        float dsum = 0.f;
        for (int j = jb; j < je; j += 8) {
            int j0 = j + g, j1 = j + 4 + g;
            bool v0 = j0 < je, v1 = j1 < je;
            unsigned s0 = (unsigned)perm[v0 ? j0 : je - 1];
            unsigned s1 = (unsigned)perm[v1 ? j1 : je - 1];
            float c0 = __half2float(ssrc[s0 * uss + usoff]);
            float c1 = __half2float(ssrc[s1 * uss + usoff]);
            unsigned u0 = hsrc[s0 * 16u + (unsigned)l4];
            unsigned u1 = hsrc[s1 * 16u + (unsigned)l4];
            float a0 = c0 + adst; a0 = a0 > 0.f ? a0 : 0.2f * a0;
            float a1 = c1 + adst; a1 = a1 > 0.f ? a1 : 0.2f * a1;
            float e0 = v0 ? __builtin_amdgcn_exp2f(a0) : 0.f;  // scores pre-scaled by log2e
            float e1 = v1 ? __builtin_amdgcn_exp2f(a1) : 0.f;
            dsum += e0 + e1;
            v2f lo0 = __builtin_amdgcn_cvt_pk_f32_fp8((int)u0, false);
            v2f hi0 = __builtin_amdgcn_cvt_pk_f32_fp8((int)u0, true);
            v2f lo1 = __builtin_amdgcn_cvt_pk_f32_fp8((int)u1, false);
            v2f hi1 = __builtin_amdgcn_cvt_pk_f32_fp8((int)u1, true);
            acc.x += lo0.x * e0 + lo1.x * e1;
            acc.y += lo0.y * e0 + lo1.y * e1;
            acc.z += hi0.x * e0 + hi1.x * e1;
            acc.w += hi0.y * e0 + hi1.y * e1;
        }
#pragma unroll
        for (int mask = 16; mask <= 32; mask <<= 1) {
            acc.x += __shfl_xor(acc.x, mask, 64);
            acc.y += __shfl_xor(acc.y, mask, 64);
            acc.z += __shfl_xor(acc.z, mask, 64);
            acc.w += __shfl_xor(acc.w, mask, 64);
            dsum  += __shfl_xor(dsum,  mask, 64);
        }
        float inv = 1.f / (dsum + 1e-16f);
        float4 v4 = make_float4(fmaxf(acc.x * inv, 0.f), fmaxf(acc.y * inv, 0.f),
                                fmaxf(acc.z * inv, 0.f), fmaxf(acc.w * inv, 0.f));
        if (g == 0) *(float4*)&srow[w][l4 * 4] = v4;  // rebroadcast layout
        float v = srow[w][t];                          // wave-coherent LDS
        if (type == 2) {
            p_ing += v;
        } else {
            if (type == 0)      p0 += v;
            else if (type == 1) p1 += v;
            else if (type == 3) p2 += v;
            else                p3 += v;
            // write fp8 row for sem_kernel: md in [0, 200000)
            if (g == 0) {
                unsigned md = (unsigned)(d < 100000 ? d : d - 100000);
                int r0 = __builtin_amdgcn_cvt_pk_fp8_f32(v4.x, v4.y, 0, false);
                int r1 = __builtin_amdgcn_cvt_pk_fp8_f32(v4.z, v4.w, r0, true);
                rows8[md * 16u + (unsigned)l4] = (unsigned)r1;
            }
        }
    }
    float vals[5] = { p_ing, p0, p1, p2, p3 };
    float* outs[5] = { pool_ing, pool_dir, pool_dir + 64, pool_dir + 128,
                       pool_dir + 192 };
    for (int i = 0; i < 5; ++i) {
        __syncthreads();
        sred[w][t] = vals[i];
        __syncthreads();
        if (w == 0)
            atomicAdd(&outs[i][t], sred[0][t] + sred[1][t] + sred[2][t] + sred[3][t]);
    }
}

// ============ sem: streaming tanh(row.Wk+bk) column-sums per type ==========
// Lane-owns-row: each lane holds one dst's fp8 row (16 u32); Wk^T is read as
// wave-UNIFORM LDS broadcasts (no per-lane LDS traffic, no conflicts).
// Tiles are type-aligned: 782 tiles per type (781 full + 16-row tail).
__global__ __launch_bounds__(256) void sem_kernel(
    const unsigned* __restrict__ rows8, const float* __restrict__ Wk,
    const float* __restrict__ bk, float* __restrict__ sem_dir)
{
    __shared__ __align__(16) float swkT[64 * 64];   // swkT[t*64+k] = Wk[k*64+t]
    __shared__ float sbk[64];
    __shared__ float ssem[256];                      // [4 types][64]
    const int tid = threadIdx.x;
    for (int i = tid; i < 4096; i += 256)
        swkT[(i & 63) * 64 + (i >> 6)] = Wk[i];
    if (tid < 64) sbk[tid] = bk[tid];
    ssem[tid] = 0.f;
    __syncthreads();

    const int lane = tid & 63, w = tid >> 6;
    const int tile = blockIdx.x * 4 + w;      // grid = 782 blocks -> 3128 tiles
    const int tt = tile / 782;                // type slot 0..3 (cooc,used,pairs,follows)
    const int loc = tile - tt * 782;
    const int row_local = loc * 64 + lane;
    const bool active = row_local < 50000;
    const unsigned md = (unsigned)(tt * 50000 + (active ? row_local : 0));

    const uint4* rp = (const uint4*)(rows8 + md * 16u);
    uint4 ua = rp[0], ub = rp[1], uc = rp[2], ud = rp[3];
    const int ttbase = tt * 64;

    for (int t = 0; t < 64; ++t) {
        float a = sbk[t];
        const float4* wrow = (const float4*)&swkT[t * 64];
        float4 wq;
#define ACC4(Q, UVAL)                                                     \
        {                                                                 \
            wq = wrow[Q];                                                 \
            v2f lo = __builtin_amdgcn_cvt_pk_f32_fp8((int)(UVAL), false); \
            v2f hi = __builtin_amdgcn_cvt_pk_f32_fp8((int)(UVAL), true);  \
            a += lo.x * wq.x + lo.y * wq.y + hi.x * wq.z + hi.y * wq.w;   \
        }
        ACC4(0, ua.x)  ACC4(1, ua.y)  ACC4(2, ua.z)  ACC4(3, ua.w)
        ACC4(4, ub.x)  ACC4(5, ub.y)  ACC4(6, ub.z)  ACC4(7, ub.w)
        ACC4(8, uc.x)  ACC4(9, uc.y)  ACC4(10, uc.z) ACC4(11, uc.w)
        ACC4(12, ud.x) ACC4(13, ud.y) ACC4(14, ud.z) ACC4(15, ud.w)
#undef ACC4
        float th = tanhf(a);
        if (!active) th = 0.f;
#pragma unroll
        for (int mask = 1; mask <= 32; mask <<= 1)
            th += __shfl_xor(th, mask, 64);
        if (lane == 0) atomicAdd(&ssem[ttbase + t], th);
    }
    __syncthreads();
    atomicAdd(&sem_dir[tid], ssem[tid]);
}

// ============ final: semantic softmax + pools + VAE head ===================
__global__ __launch_bounds__(64) void final_kernel(
    const float* __restrict__ pool_ing, const float* __restrict__ pool_dir,
    const float* __restrict__ sem_dir, const float* __restrict__ q,
    const float* __restrict__ cond, const float* __restrict__ eps,
    const float* __restrict__ W_mu, const float* __restrict__ b_mu,
    const float* __restrict__ W_lv, const float* __restrict__ b_lv,
    const float* __restrict__ W_fc3, const float* __restrict__ b_fc3,
    const float* __restrict__ W_fc2, const float* __restrict__ b_fc2,
    float* __restrict__ out)
{
    __shared__ float gr[136];
    __shared__ float sc[4], attn[4];
    __shared__ float z[32], hfc[64];
    int t = threadIdx.x;  // 64 threads
    if (t < 4) {
        float s = 0.f;
        for (int f = 0; f < 64; ++f)
            s += (sem_dir[t * 64 + f] / (float)N_DIR) * q[f];
        sc[t] = s;
    }
    gr[t] = pool_ing[t] / (float)N_ING;   // out_ing == o_cont (T=1 softmax)
    __syncthreads();
    if (t == 0) {
        float m = fmaxf(fmaxf(sc[0], sc[1]), fmaxf(sc[2], sc[3]));
        float ssum = 0.f;
        for (int i = 0; i < 4; ++i) { attn[i] = expf(sc[i] - m); ssum += attn[i]; }
        for (int i = 0; i < 4; ++i) attn[i] /= ssum;
    }
    __syncthreads();
    {
        float v = 0.f;
        for (int tt = 0; tt < 4; ++tt)
            v += attn[tt] * (pool_dir[tt * 64 + t] / (float)N_DIR);
        gr[64 + t] = v;
    }
    if (t < 8) gr[128 + t] = cond[t];
    __syncthreads();
    if (t < 32) {
        float m = b_mu[t], lv = b_lv[t];
        for (int i = 0; i < 136; ++i) {
            float g = gr[i];
            m  += g * W_mu[i * 32 + t];
            lv += g * W_lv[i * 32 + t];
        }
        out[16 + t] = m;
        out[48 + t] = lv;
        z[t] = m + eps[t] * expf(0.5f * lv);
    }
    __syncthreads();
    {
        float v = b_fc3[t];
        for (int j = 0; j < 32; ++j) v += z[j] * W_fc3[j * 64 + t];
        hfc[t] = fmaxf(v, 0.f);
    }
    __syncthreads();
    if (t < 16) {
        float v = b_fc2[t];
        for (int f = 0; f < 64; ++f) v += hfc[f] * W_fc2[f * 16 + t];
        out[t] = tanhf(v);
    }
}

extern "C" void kernel_launch(void* const* d_in, const int* in_sizes, int n_in,
                              void* d_out, int out_size, void* d_ws, size_t ws_size,
                              hipStream_t stream) {
    const float* x_ing = (const float*)d_in[0];
    const float* x_dir = (const float*)d_in[1];
    const float* cond  = (const float*)d_in[2];
    const float* eps   = (const float*)d_in[3];
    const int* ei_cooc     = (const int*)d_in[4];
    const int* ei_used     = (const int*)d_in[5];
    const int* ei_contains = (const int*)d_in[6];
    const int* ei_pairs    = (const int*)d_in[7];
    const int* ei_follows  = (const int*)d_in[8];
    const float* W_pi = (const float*)d_in[9];
    const float* b_pi = (const float*)d_in[10];
    const float* W_pd = (const float*)d_in[11];
    const float* b_pd = (const float*)d_in[12];
    const float* Wk   = (const float*)d_in[13];
    const float* bk   = (const float*)d_in[14];
    const float* q    = (const float*)d_in[15];
    const float* W_mu = (const float*)d_in[16];
    const float* b_mu = (const float*)d_in[17];
    const float* W_lv = (const float*)d_in[18];
    const float* b_lv = (const float*)d_in[19];
    const float* W_fc3 = (const float*)d_in[20];
    const float* b_fc3 = (const float*)d_in[21];
    const float* W_fc2 = (const float*)d_in[22];
    const float* b_fc2 = (const float*)d_in[23];
    const float* as_cooc     = (const float*)d_in[24];
    const float* ad_cooc     = (const float*)d_in[25];
    const float* as_used     = (const float*)d_in[26];
    const float* ad_used     = (const float*)d_in[27];
    const float* as_contains = (const float*)d_in[28];
    const float* ad_contains = (const float*)d_in[29];
    const float* as_pairs    = (const float*)d_in[30];
    const float* ad_pairs    = (const float*)d_in[31];
    const float* as_follows  = (const float*)d_in[32];
    const float* ad_follows  = (const float*)d_in[33];

    // ---- workspace layout ----
    unsigned* bpair = (unsigned*)d_ws;                        // 5M u32 (20 MB)
    unsigned* h8_ing = bpair + (size_t)5 * NE;                // N_ING*16 u32
    unsigned* h8_dir = h8_ing + (size_t)N_ING * 16;           // N_DIR*16
    __half* s_ing = (__half*)(h8_dir + (size_t)N_DIR * 16);   // N_ING*12 fp16
    __half* s_dir = s_ing + (size_t)N_ING * 12;               // N_DIR*28 fp16
    int*   perm  = (int*)(s_dir + (size_t)N_DIR * 28);        // 5M
    int*   blockcnt  = perm + (size_t)5 * NE;                 // 80*4688
    int*   blockbase = blockcnt + (size_t)NBK * NBUCK;        // 80*4688
    int*   bbase  = blockbase + (size_t)NBK * NBUCK;          // 4688
    int*   btot   = bbase + NBUCK;                            // 4688
    int*   start  = btot + NBUCK;                             // 300K
    int*   cnt    = start + NDST_TOTAL;                       // 300K
    int*   cursor = cnt + NDST_TOTAL;                         // 1  (zeroed region)
    float* pool_ing = (float*)(cursor + 1);                   // 64
    float* pool_dir = pool_ing + 64;                          // 4*64
    float* sem_dir  = pool_dir + 256;                         // 4*64
    unsigned* rows8 = bpair;   // bpair is dead after k4: reuse for 200K*16 u32

    // tiny memset: cursor + pools + sem
    hipMemsetAsync(cursor, 0, (1 + 64 + 256 + 256) * sizeof(int), stream);

    // kA: bucket histogram (LDS-only atomics) + fused proj/fp8/fp16-score
    kA_kernel<<<NBK + PB_ING + PB_DIR, 256, 0, stream>>>(
        ei_cooc, ei_used, ei_contains, ei_pairs, ei_follows, blockcnt,
        x_ing, W_pi, b_pi, as_cooc, as_used, ad_contains, h8_ing, s_ing,
        x_dir, W_pd, b_pd, ad_cooc, ad_used, as_contains, as_pairs, ad_pairs,
        as_follows, ad_follows, h8_dir, s_dir);

    // k2: bucket scan -> bases (64 buckets x 4 threads per block)
    k2_kernel<<<(NBUCK + 63) / 64, 256, 0, stream>>>(
        blockcnt, blockbase, bbase, btot, cursor);

    // k3: bucket scatter (LDS cursors, u32 packed)
    k3_kernel<<<NBK, 256, 0, stream>>>(
        ei_cooc, ei_used, ei_contains, ei_pairs, ei_follows, blockbase, bpair);

    // k4: per-bucket counting sort -> perm + start/cnt
    k4_kernel<<<NBUCK, 256, 0, stream>>>(bpair, bbase, btot, perm, start, cnt);

    // agg over all 300K dst segments; writes fp8 rows for the sem pass
    agg_all_kernel<<<2048, 256, 0, stream>>>(
        perm, start, cnt, h8_ing, h8_dir, s_ing, s_dir, rows8,
        pool_ing, pool_dir);

    // sem: streaming per-type tanh(row.Wk+bk) column sums (250K rows)
    sem_kernel<<<782, 256, 0, stream>>>(rows8, Wk, bk, sem_dir);

    final_kernel<<<1, 64, 0, stream>>>(
        pool_ing, pool_dir, sem_dir, q, cond, eps,
        W_mu, b_mu, W_lv, b_lv, W_fc3, b_fc3, W_fc2, b_fc2, (float*)d_out);
}

// Round 4
// 521.465 us; speedup vs baseline: 2.0629x; 1.1388x over previous
//
#include <hip/hip_runtime.h>
#include <hip/hip_fp16.h>
#include <math.h>

#define N_ING 100000
#define N_DIR 50000
#define NE    1000000
#define NDST_TOTAL 300000   // 50K(cooc)+50K(used)+100K(contains)+50K(pairs)+50K(follows)
#define NBUCK 4688          // ceil(300000/64): 64 dst nodes per bucket
#define BA    16            // hist/scatter blocks per edge type
#define NBK   (5 * BA)      // 80
#define I4PT  (NE / 4)      // int4s per type
#define PB_ING 384
#define PB_DIR 192
#define LOG2E 1.442695041f

typedef float v2f __attribute__((ext_vector_type(2)));
typedef __attribute__((ext_vector_type(8))) short bf16x8;
typedef __attribute__((ext_vector_type(4))) float f32x4;

// ============ kA: bucket histogram (LDS atomics) + fused proj+score ========
// Attention vectors pre-scaled by log2(e) so agg uses bare v_exp_f32 (exp2).
__global__ __launch_bounds__(256) void kA_kernel(
    const int* __restrict__ e0, const int* __restrict__ e1,
    const int* __restrict__ e2, const int* __restrict__ e3,
    const int* __restrict__ e4, int* __restrict__ blockcnt,
    const float* __restrict__ x_ing, const float* __restrict__ W_pi,
    const float* __restrict__ b_pi,
    const float* __restrict__ as_cooc, const float* __restrict__ as_used,
    const float* __restrict__ ad_contains,
    unsigned* __restrict__ h8_ing, __half* __restrict__ s_ing,
    const float* __restrict__ x_dir, const float* __restrict__ W_pd,
    const float* __restrict__ b_pd,
    const float* __restrict__ ad_cooc, const float* __restrict__ ad_used,
    const float* __restrict__ as_contains, const float* __restrict__ as_pairs,
    const float* __restrict__ ad_pairs, const float* __restrict__ as_follows,
    const float* __restrict__ ad_follows,
    unsigned* __restrict__ h8_dir, __half* __restrict__ s_dir)
{
    __shared__ int hist[NBUCK];
    __shared__ float sW[16 * 64];
    __shared__ float sbb[64];
    __shared__ float satt[7 * 64];
    __shared__ float sx[4][16];
    __shared__ float srow[4][64];

    const int bid = blockIdx.x;
    const int tid = threadIdx.x;
    if (bid < NBK) {
        // ---------- bucket histogram, one row per block ----------
        const int type = bid / BA, blk = bid % BA;
        const int* ei = type == 0 ? e0 : type == 1 ? e1 : type == 2 ? e2
                      : type == 3 ? e3 : e4;
        const int base = type == 0 ? 0 : type == 1 ? 50000 : type == 2 ? 100000
                       : type == 3 ? 200000 : 250000;
        for (int i = tid; i < NBUCK; i += 256) hist[i] = 0;
        __syncthreads();
        const int4* d4 = (const int4*)(ei + NE);
        for (int i = blk * 256 + tid; i < I4PT; i += BA * 256) {
            int4 d = d4[i];
            atomicAdd(&hist[(base + d.x) >> 6], 1);
            atomicAdd(&hist[(base + d.y) >> 6], 1);
            atomicAdd(&hist[(base + d.z) >> 6], 1);
            atomicAdd(&hist[(base + d.w) >> 6], 1);
        }
        __syncthreads();
        int* row = blockcnt + (size_t)bid * NBUCK;
        for (int i = tid; i < NBUCK; i += 256) row[i] = hist[i];
    } else if (bid < NBK + PB_ING) {
        // ---------- proj + fp8 pack + fp16 scores, ingredient nodes ---------
        const int g = tid >> 6, t = tid & 63;
        for (int i = tid; i < 16 * 64; i += 256) sW[i] = W_pi[i];
        if (tid < 64) {
            sbb[tid] = b_pi[tid];
            satt[tid]       = as_cooc[tid] * LOG2E;
            satt[64 + tid]  = as_used[tid] * LOG2E;
            satt[128 + tid] = ad_contains[tid] * LOG2E;
        }
        __syncthreads();
        for (int q = bid - NBK; q < N_ING / 4; q += PB_ING) {
            int n = q * 4 + g;
            if (t < 16) sx[g][t] = x_ing[(size_t)n * 16 + t];
            __syncthreads();
            float s = sbb[t];
#pragma unroll
            for (int i = 0; i < 16; ++i) s += sx[g][i] * sW[i * 64 + t];
            srow[g][t] = s;
            __syncthreads();
            if (t < 16) {
                int w0 = __builtin_amdgcn_cvt_pk_fp8_f32(srow[g][t * 4], srow[g][t * 4 + 1], 0, false);
                int w  = __builtin_amdgcn_cvt_pk_fp8_f32(srow[g][t * 4 + 2], srow[g][t * 4 + 3], w0, true);
                h8_ing[(size_t)n * 16 + t] = (unsigned)w;
            }
            if (t < 12) {
                int slot = t >> 2, hh = t & 3;
                float sc = 0.f;
#pragma unroll
                for (int d = 0; d < 16; ++d)
                    sc += srow[g][hh * 16 + d] * satt[slot * 64 + hh * 16 + d];
                s_ing[(size_t)n * 12 + t] = __float2half(sc);
            }
            __syncthreads();
        }
    } else {
        // ---------- proj + fp8 pack + fp16 scores, direction nodes ----------
        const int g = tid >> 6, t = tid & 63;
        for (int i = tid; i < 8 * 64; i += 256) sW[i] = W_pd[i];
        if (tid < 64) {
            sbb[tid] = b_pd[tid];
            satt[tid]        = ad_cooc[tid] * LOG2E;
            satt[64  + tid]  = ad_used[tid] * LOG2E;
            satt[128 + tid]  = as_contains[tid] * LOG2E;
            satt[192 + tid]  = as_pairs[tid] * LOG2E;
            satt[256 + tid]  = ad_pairs[tid] * LOG2E;
            satt[320 + tid]  = as_follows[tid] * LOG2E;
            satt[384 + tid]  = ad_follows[tid] * LOG2E;
        }
        __syncthreads();
        for (int q = bid - NBK - PB_ING; q < N_DIR / 4; q += PB_DIR) {
            int n = q * 4 + g;
            if (t < 8) sx[g][t] = x_dir[(size_t)n * 8 + t];
            __syncthreads();
            float s = sbb[t];
#pragma unroll
            for (int i = 0; i < 8; ++i) s += sx[g][i] * sW[i * 64 + t];
            srow[g][t] = s;
            __syncthreads();
            if (t < 16) {
                int w0 = __builtin_amdgcn_cvt_pk_fp8_f32(srow[g][t * 4], srow[g][t * 4 + 1], 0, false);
                int w  = __builtin_amdgcn_cvt_pk_fp8_f32(srow[g][t * 4 + 2], srow[g][t * 4 + 3], w0, true);
                h8_dir[(size_t)n * 16 + t] = (unsigned)w;
            }
            if (t < 28) {
                int slot = t >> 2, hh = t & 3;
                float sc = 0.f;
#pragma unroll
                for (int d = 0; d < 16; ++d)
                    sc += srow[g][hh * 16 + d] * satt[slot * 64 + hh * 16 + d];
                s_dir[(size_t)n * 28 + t] = __float2half(sc);
            }
            __syncthreads();
        }
    }
}

// ============ k2: bucket totals + bases, 64 buckets x 4 threads per block ==
__global__ __launch_bounds__(256) void k2_kernel(
    const int* __restrict__ blockcnt, int* __restrict__ blockbase,
    int* __restrict__ bbase, int* __restrict__ btot, int* __restrict__ cursor)
{
    __shared__ int part[4][64];
    __shared__ int tots[64];
    __shared__ int scn[64];
    __shared__ int bw;
    const int tid = threadIdx.x;
    const int kq = tid >> 6, bl = tid & 63;   // 4 k-quarters x 64 buckets
    const int b = blockIdx.x * 64 + bl;
    const int K = NBK / 4;                    // 20 rows per quarter
    int ps = 0;
    if (b < NBUCK)
        for (int k = kq * K; k < kq * K + K; ++k)
            ps += blockcnt[(size_t)k * NBUCK + b];
    part[kq][bl] = ps;
    __syncthreads();
    if (tid < 64) {
        int t = part[0][tid] + part[1][tid] + part[2][tid] + part[3][tid];
        tots[tid] = t;
        scn[tid] = t;
    }
    __syncthreads();
    for (int off = 1; off < 64; off <<= 1) {
        int v = 0;
        if (tid < 64 && tid >= off) v = scn[tid - off];
        __syncthreads();
        if (tid < 64) scn[tid] += v;
        __syncthreads();
    }
    if (tid == 63) bw = atomicAdd(cursor, scn[63]);
    __syncthreads();
    if (b < NBUCK) {
        int bs = bw + scn[bl] - tots[bl];     // exclusive bucket base
        if (kq == 0) {
            bbase[b] = bs;
            btot[b] = tots[bl];
        }
        int run = bs;
        for (int q = 0; q < kq; ++q) run += part[q][bl];
        for (int k = kq * K; k < kq * K + K; ++k) {
            blockbase[(size_t)k * NBUCK + b] = run;
            run += blockcnt[(size_t)k * NBUCK + b];
        }
    }
}

// ============ k3: bucket scatter (LDS cursors, packed u32 entries) =========
__global__ __launch_bounds__(256) void k3_kernel(
    const int* __restrict__ e0, const int* __restrict__ e1,
    const int* __restrict__ e2, const int* __restrict__ e3,
    const int* __restrict__ e4, const int* __restrict__ blockbase,
    unsigned* __restrict__ bpair)
{
    __shared__ int cur[NBUCK];
    const int bid = blockIdx.x, tid = threadIdx.x;
    const int type = bid / BA, blk = bid % BA;
    const int* ei = type == 0 ? e0 : type == 1 ? e1 : type == 2 ? e2
                  : type == 3 ? e3 : e4;
    const int base = type == 0 ? 0 : type == 1 ? 50000 : type == 2 ? 100000
                   : type == 3 ? 200000 : 250000;
    const int* row = blockbase + (size_t)bid * NBUCK;
    for (int i = tid; i < NBUCK; i += 256) cur[i] = row[i];
    __syncthreads();
    const int4* s4 = (const int4*)ei;
    const int4* d4 = (const int4*)(ei + NE);
    for (int i = blk * 256 + tid; i < I4PT; i += BA * 256) {
        int4 s = s4[i];
        int4 d = d4[i];
        int g0 = base + d.x, g1 = base + d.y, g2 = base + d.z, g3 = base + d.w;
        int p0 = atomicAdd(&cur[g0 >> 6], 1);
        int p1 = atomicAdd(&cur[g1 >> 6], 1);
        int p2 = atomicAdd(&cur[g2 >> 6], 1);
        int p3 = atomicAdd(&cur[g3 >> 6], 1);
        bpair[p0] = ((unsigned)(g0 & 63) << 17) | (unsigned)s.x;
        bpair[p1] = ((unsigned)(g1 & 63) << 17) | (unsigned)s.y;
        bpair[p2] = ((unsigned)(g2 & 63) << 17) | (unsigned)s.z;
        bpair[p3] = ((unsigned)(g3 & 63) << 17) | (unsigned)s.w;
    }
}

// ============ k4: per-bucket counting sort -> perm + start/cnt =============
__global__ __launch_bounds__(256) void k4_kernel(
    const unsigned* __restrict__ bpair, const int* __restrict__ bbase,
    const int* __restrict__ btot, int* __restrict__ perm,
    int* __restrict__ start, int* __restrict__ cnt)
{
    __shared__ int h[64], sc[64], cu[64];
    const int b = blockIdx.x, tid = threadIdx.x;
    const int jb = bbase[b], n = btot[b];
    if (tid < 64) h[tid] = 0;
    __syncthreads();
    for (int i = tid; i < n; i += 256)
        atomicAdd(&h[bpair[jb + i] >> 17], 1);
    __syncthreads();
    if (tid == 0) {
        int r = 0;
        for (int i = 0; i < 64; ++i) { sc[i] = r; cu[i] = r; r += h[i]; }
    }
    __syncthreads();
    if (tid < 64) {
        int dg = b * 64 + tid;
        if (dg < NDST_TOTAL) {
            start[dg] = jb + sc[tid];
            cnt[dg] = h[tid];
        }
    }
    for (int i = tid; i < n; i += 256) {
        unsigned p = bpair[jb + i];
        int pos = atomicAdd(&cu[p >> 17], 1);
        perm[jb + pos] = (int)(p & 0x1FFFF);
    }
}

// ============ fused aggregation: fp8 rows, fp16 scores, 16 edges/iter ======
// R3 structure (VGPR-lean, occupancy-protected) with the edge loop widened
// 8 -> 16 edges/iter: 4 independent gather pairs in flight per wave instead
// of 2, to cover the ~200ns L2-miss->LLC latency (agg is gather-latency
// bound: FETCH ~= algorithmic 5M x 64B with ~0% L2 hit).
__global__ __launch_bounds__(256) void agg_all_kernel(
    const int* __restrict__ perm, const int* __restrict__ start,
    const int* __restrict__ cnttot,
    const unsigned* __restrict__ h8_ing, const unsigned* __restrict__ h8_dir,
    const __half* __restrict__ s_ing, const __half* __restrict__ s_dir,
    unsigned* __restrict__ rows8,
    float* __restrict__ pool_ing, float* __restrict__ pool_dir)
{
    __shared__ __align__(16) float srow[4][64];
    __shared__ float sred[4][64];
    const int t = threadIdx.x & 63, w = threadIdx.x >> 6;
    const int g  = t >> 4;       // edge group 0..3
    const int l4 = t & 15;       // feature quad: 4*l4 .. 4*l4+3
    const int hq = l4 >> 2;      // head of my features

    float p_ing = 0.f;
    float p0 = 0.f, p1 = 0.f, p2 = 0.f, p3 = 0.f;
    const int nwaves = gridDim.x * 4;
    for (int d = blockIdx.x * 4 + w; d < NDST_TOTAL; d += nwaves) {
        int type, ld;
        const __half *ssrc, *sdst;
        const unsigned* hsrc;
        unsigned uss, uds; int soff, doff;
        if (d < 50000)       { type = 0; ld = d;          ssrc = s_ing; uss = 12; soff = 0;  sdst = s_dir; uds = 28; doff = 0;  hsrc = h8_ing; }
        else if (d < 100000) { type = 1; ld = d - 50000;  ssrc = s_ing; uss = 12; soff = 4;  sdst = s_dir; uds = 28; doff = 4;  hsrc = h8_ing; }
        else if (d < 200000) { type = 2; ld = d - 100000; ssrc = s_dir; uss = 28; soff = 8;  sdst = s_ing; uds = 12; doff = 8;  hsrc = h8_dir; }
        else if (d < 250000) { type = 3; ld = d - 200000; ssrc = s_dir; uss = 28; soff = 12; sdst = s_dir; uds = 28; doff = 16; hsrc = h8_dir; }
        else                 { type = 4; ld = d - 250000; ssrc = s_dir; uss = 28; soff = 20; sdst = s_dir; uds = 28; doff = 24; hsrc = h8_dir; }
        float adst = __half2float(sdst[(unsigned)ld * uds + (unsigned)(doff + hq)]);
        const unsigned usoff = (unsigned)(soff + hq);
        int jb = start[d], je = jb + cnttot[d];
        int jl = je - 1;
        float4 acc = make_float4(0.f, 0.f, 0.f, 0.f);
        float dsum = 0.f;
        for (int j = jb; j < je; j += 16) {
            int j0 = j + g, j1 = j + 4 + g, j2 = j + 8 + g, j3 = j + 12 + g;
            bool v0 = j0 < je, v1 = j1 < je, v2 = j2 < je, v3 = j3 < je;
            unsigned s0 = (unsigned)perm[v0 ? j0 : jl];
            unsigned s1 = (unsigned)perm[v1 ? j1 : jl];
            unsigned s2 = (unsigned)perm[v2 ? j2 : jl];
            unsigned s3 = (unsigned)perm[v3 ? j3 : jl];
            float c0 = __half2float(ssrc[s0 * uss + usoff]);
            float c1 = __half2float(ssrc[s1 * uss + usoff]);
            float c2 = __half2float(ssrc[s2 * uss + usoff]);
            float c3 = __half2float(ssrc[s3 * uss + usoff]);
            unsigned u0 = hsrc[s0 * 16u + (unsigned)l4];
            unsigned u1 = hsrc[s1 * 16u + (unsigned)l4];
            unsigned u2 = hsrc[s2 * 16u + (unsigned)l4];
            unsigned u3 = hsrc[s3 * 16u + (unsigned)l4];
            float a0 = c0 + adst; a0 = a0 > 0.f ? a0 : 0.2f * a0;
            float a1 = c1 + adst; a1 = a1 > 0.f ? a1 : 0.2f * a1;
            float a2 = c2 + adst; a2 = a2 > 0.f ? a2 : 0.2f * a2;
            float a3 = c3 + adst; a3 = a3 > 0.f ? a3 : 0.2f * a3;
            float e0 = v0 ? __builtin_amdgcn_exp2f(a0) : 0.f;  // scores pre-scaled by log2e
            float e1 = v1 ? __builtin_amdgcn_exp2f(a1) : 0.f;
            float e2 = v2 ? __builtin_amdgcn_exp2f(a2) : 0.f;
            float e3 = v3 ? __builtin_amdgcn_exp2f(a3) : 0.f;
            dsum += (e0 + e1) + (e2 + e3);
            v2f lo0 = __builtin_amdgcn_cvt_pk_f32_fp8((int)u0, false);
            v2f hi0 = __builtin_amdgcn_cvt_pk_f32_fp8((int)u0, true);
            v2f lo1 = __builtin_amdgcn_cvt_pk_f32_fp8((int)u1, false);
            v2f hi1 = __builtin_amdgcn_cvt_pk_f32_fp8((int)u1, true);
            v2f lo2 = __builtin_amdgcn_cvt_pk_f32_fp8((int)u2, false);
            v2f hi2 = __builtin_amdgcn_cvt_pk_f32_fp8((int)u2, true);
            v2f lo3 = __builtin_amdgcn_cvt_pk_f32_fp8((int)u3, false);
            v2f hi3 = __builtin_amdgcn_cvt_pk_f32_fp8((int)u3, true);
            acc.x += (lo0.x * e0 + lo1.x * e1) + (lo2.x * e2 + lo3.x * e3);
            acc.y += (lo0.y * e0 + lo1.y * e1) + (lo2.y * e2 + lo3.y * e3);
            acc.z += (hi0.x * e0 + hi1.x * e1) + (hi2.x * e2 + hi3.x * e3);
            acc.w += (hi0.y * e0 + hi1.y * e1) + (hi2.y * e2 + hi3.y * e3);
        }
#pragma unroll
        for (int mask = 16; mask <= 32; mask <<= 1) {
            acc.x += __shfl_xor(acc.x, mask, 64);
            acc.y += __shfl_xor(acc.y, mask, 64);
            acc.z += __shfl_xor(acc.z, mask, 64);
            acc.w += __shfl_xor(acc.w, mask, 64);
            dsum  += __shfl_xor(dsum,  mask, 64);
        }
        float inv = 1.f / (dsum + 1e-16f);
        float4 v4 = make_float4(fmaxf(acc.x * inv, 0.f), fmaxf(acc.y * inv, 0.f),
                                fmaxf(acc.z * inv, 0.f), fmaxf(acc.w * inv, 0.f));
        if (g == 0) *(float4*)&srow[w][l4 * 4] = v4;  // rebroadcast layout
        float v = srow[w][t];                          // wave-coherent LDS
        if (type == 2) {
            p_ing += v;
        } else {
            if (type == 0)      p0 += v;
            else if (type == 1) p1 += v;
            else if (type == 3) p2 += v;
            else                p3 += v;
            // write fp8 row for sem_kernel: md in [0, 200000)
            if (g == 0) {
                unsigned md = (unsigned)(d < 100000 ? d : d - 100000);
                int r0 = __builtin_amdgcn_cvt_pk_fp8_f32(v4.x, v4.y, 0, false);
                int r1 = __builtin_amdgcn_cvt_pk_fp8_f32(v4.z, v4.w, r0, true);
                rows8[md * 16u + (unsigned)l4] = (unsigned)r1;
            }
        }
    }
    float vals[5] = { p_ing, p0, p1, p2, p3 };
    float* outs[5] = { pool_ing, pool_dir, pool_dir + 64, pool_dir + 128,
                       pool_dir + 192 };
    for (int i = 0; i < 5; ++i) {
        __syncthreads();
        sred[w][t] = vals[i];
        __syncthreads();
        if (w == 0)
            atomicAdd(&outs[i][t], sred[0][t] + sred[1][t] + sred[2][t] + sred[3][t]);
    }
}

// ============ sem: MFMA GEMM tanh(R.Wk+bk) column-sums per type ============
// D = R[200K x 64] . Wk[64 x 64] via mfma_f32_16x16x32_bf16; per-wave M-tile
// = 16 rows (50000 = 3125*16, so tiles never span types). A = fp8 rows
// converted to bf16 (exact); B = Wk RNE-rounded to bf16. A and B fragments
// use the SAME assumed k-mapping (k = ks*32 + (lane>>4)*8 + j), so any hw
// k-permutation cancels. C/D mapping is the verified col=lane&15,
// row=(lane>>4)*4+reg. Epilogue: fast tanh = (t-1)*rcp(t+1), t=exp2(2x*log2e),
// x clamped to +-15; column-sum over reg then shfl_xor(16,32).
__global__ __launch_bounds__(256) void sem_kernel(
    const unsigned* __restrict__ rows8, const float* __restrict__ Wk,
    const float* __restrict__ bk, float* __restrict__ sem_dir)
{
    __shared__ float swk[4096];
    __shared__ float ssem[256];
    const int tid = threadIdx.x;
    for (int i = tid; i < 4096; i += 256) swk[i] = Wk[i];
    ssem[tid] = 0.f;
    __syncthreads();

    const int lane = tid & 63, w = tid >> 6;
    const int col = lane & 15, kg = lane >> 4;

    // B fragments (shared by all tiles): bfr[nt][ks], k = ks*32 + kg*8 + j
    bf16x8 bfr[4][2];
    float biasv[4];
#pragma unroll
    for (int nt = 0; nt < 4; ++nt) {
        biasv[nt] = bk[nt * 16 + col];
#pragma unroll
        for (int ks = 0; ks < 2; ++ks) {
            bf16x8 bb;
#pragma unroll
            for (int j = 0; j < 8; ++j) {
                int k = ks * 32 + kg * 8 + j;
                unsigned u = __builtin_bit_cast(unsigned, swk[k * 64 + nt * 16 + col]);
                u = u + 0x7FFFu + ((u >> 16) & 1u);   // round-to-nearest-even
                bb[j] = (short)(u >> 16);
            }
            bfr[nt][ks] = bb;
        }
    }

    const int gw = blockIdx.x * 4 + w;
    const int nw = gridDim.x * 4;
    for (int tile = gw; tile < 12500; tile += nw) {
        const int tt = tile / 3125;                 // type slot 0..3
        const unsigned* rp = rows8 + (unsigned)(tile * 16 + col) * 16u;
        // A fragments: row = col(=lane&15), k = ks*32 + kg*8 + j
        bf16x8 afr[2];
#pragma unroll
        for (int ks = 0; ks < 2; ++ks) {
            uint2 uu = *(const uint2*)(rp + ks * 8 + kg * 2);
            v2f l0 = __builtin_amdgcn_cvt_pk_f32_fp8((int)uu.x, false);
            v2f h0 = __builtin_amdgcn_cvt_pk_f32_fp8((int)uu.x, true);
            v2f l1 = __builtin_amdgcn_cvt_pk_f32_fp8((int)uu.y, false);
            v2f h1 = __builtin_amdgcn_cvt_pk_f32_fp8((int)uu.y, true);
            bf16x8 aa;   // fp8 values are exactly representable in bf16: truncate
            aa[0] = (short)(__builtin_bit_cast(unsigned, l0.x) >> 16);
            aa[1] = (short)(__builtin_bit_cast(unsigned, l0.y) >> 16);
            aa[2] = (short)(__builtin_bit_cast(unsigned, h0.x) >> 16);
            aa[3] = (short)(__builtin_bit_cast(unsigned, h0.y) >> 16);
            aa[4] = (short)(__builtin_bit_cast(unsigned, l1.x) >> 16);
            aa[5] = (short)(__builtin_bit_cast(unsigned, l1.y) >> 16);
            aa[6] = (short)(__builtin_bit_cast(unsigned, h1.x) >> 16);
            aa[7] = (short)(__builtin_bit_cast(unsigned, h1.y) >> 16);
            afr[ks] = aa;
        }
#pragma unroll
        for (int nt = 0; nt < 4; ++nt) {
            f32x4 acc = {0.f, 0.f, 0.f, 0.f};
            acc = __builtin_amdgcn_mfma_f32_16x16x32_bf16(afr[0], bfr[nt][0], acc, 0, 0, 0);
            acc = __builtin_amdgcn_mfma_f32_16x16x32_bf16(afr[1], bfr[nt][1], acc, 0, 0, 0);
            float s = 0.f;
#pragma unroll
            for (int reg = 0; reg < 4; ++reg) {
                float x = acc[reg] + biasv[nt];
                x = fminf(fmaxf(x, -15.f), 15.f);
                float e = __builtin_amdgcn_exp2f(x * (2.f * LOG2E));
                s += (e - 1.f) * __builtin_amdgcn_rcpf(e + 1.f);
            }
            s += __shfl_xor(s, 16, 64);
            s += __shfl_xor(s, 32, 64);
            if (lane < 16) atomicAdd(&ssem[tt * 64 + nt * 16 + col], s);
        }
    }
    __syncthreads();
    atomicAdd(&sem_dir[tid], ssem[tid]);
}

// ============ final: semantic softmax + pools + VAE head ===================
__global__ __launch_bounds__(64) void final_kernel(
    const float* __restrict__ pool_ing, const float* __restrict__ pool_dir,
    const float* __restrict__ sem_dir, const float* __restrict__ q,
    const float* __restrict__ cond, const float* __restrict__ eps,
    const float* __restrict__ W_mu, const float* __restrict__ b_mu,
    const float* __restrict__ W_lv, const float* __restrict__ b_lv,
    const float* __restrict__ W_fc3, const float* __restrict__ b_fc3,
    const float* __restrict__ W_fc2, const float* __restrict__ b_fc2,
    float* __restrict__ out)
{
    __shared__ float gr[136];
    __shared__ float sc[4], attn[4];
    __shared__ float z[32], hfc[64];
    int t = threadIdx.x;  // 64 threads
    if (t < 4) {
        float s = 0.f;
        for (int f = 0; f < 64; ++f)
            s += (sem_dir[t * 64 + f] / (float)N_DIR) * q[f];
        sc[t] = s;
    }
    gr[t] = pool_ing[t] / (float)N_ING;   // out_ing == o_cont (T=1 softmax)
    __syncthreads();
    if (t == 0) {
        float m = fmaxf(fmaxf(sc[0], sc[1]), fmaxf(sc[2], sc[3]));
        float ssum = 0.f;
        for (int i = 0; i < 4; ++i) { attn[i] = expf(sc[i] - m); ssum += attn[i]; }
        for (int i = 0; i < 4; ++i) attn[i] /= ssum;
    }
    __syncthreads();
    {
        float v = 0.f;
        for (int tt = 0; tt < 4; ++tt)
            v += attn[tt] * (pool_dir[tt * 64 + t] / (float)N_DIR);
        gr[64 + t] = v;
    }
    if (t < 8) gr[128 + t] = cond[t];
    __syncthreads();
    if (t < 32) {
        float m = b_mu[t], lv = b_lv[t];
        for (int i = 0; i < 136; ++i) {
            float g = gr[i];
            m  += g * W_mu[i * 32 + t];
            lv += g * W_lv[i * 32 + t];
        }
        out[16 + t] = m;
        out[48 + t] = lv;
        z[t] = m + eps[t] * expf(0.5f * lv);
    }
    __syncthreads();
    {
        float v = b_fc3[t];
        for (int j = 0; j < 32; ++j) v += z[j] * W_fc3[j * 64 + t];
        hfc[t] = fmaxf(v, 0.f);
    }
    __syncthreads();
    if (t < 16) {
        float v = b_fc2[t];
        for (int f = 0; f < 64; ++f) v += hfc[f] * W_fc2[f * 16 + t];
        out[t] = tanhf(v);
    }
}

extern "C" void kernel_launch(void* const* d_in, const int* in_sizes, int n_in,
                              void* d_out, int out_size, void* d_ws, size_t ws_size,
                              hipStream_t stream) {
    const float* x_ing = (const float*)d_in[0];
    const float* x_dir = (const float*)d_in[1];
    const float* cond  = (const float*)d_in[2];
    const float* eps   = (const float*)d_in[3];
    const int* ei_cooc     = (const int*)d_in[4];
    const int* ei_used     = (const int*)d_in[5];
    const int* ei_contains = (const int*)d_in[6];
    const int* ei_pairs    = (const int*)d_in[7];
    const int* ei_follows  = (const int*)d_in[8];
    const float* W_pi = (const float*)d_in[9];
    const float* b_pi = (const float*)d_in[10];
    const float* W_pd = (const float*)d_in[11];
    const float* b_pd = (const float*)d_in[12];
    const float* Wk   = (const float*)d_in[13];
    const float* bk   = (const float*)d_in[14];
    const float* q    = (const float*)d_in[15];
    const float* W_mu = (const float*)d_in[16];
    const float* b_mu = (const float*)d_in[17];
    const float* W_lv = (const float*)d_in[18];
    const float* b_lv = (const float*)d_in[19];
    const float* W_fc3 = (const float*)d_in[20];
    const float* b_fc3 = (const float*)d_in[21];
    const float* W_fc2 = (const float*)d_in[22];
    const float* b_fc2 = (const float*)d_in[23];
    const float* as_cooc     = (const float*)d_in[24];
    const float* ad_cooc     = (const float*)d_in[25];
    const float* as_used     = (const float*)d_in[26];
    const float* ad_used     = (const float*)d_in[27];
    const float* as_contains = (const float*)d_in[28];
    const float* ad_contains = (const float*)d_in[29];
    const float* as_pairs    = (const float*)d_in[30];
    const float* ad_pairs    = (const float*)d_in[31];
    const float* as_follows  = (const float*)d_in[32];
    const float* ad_follows  = (const float*)d_in[33];

    // ---- workspace layout ----
    unsigned* bpair = (unsigned*)d_ws;                        // 5M u32 (20 MB)
    unsigned* h8_ing = bpair + (size_t)5 * NE;                // N_ING*16 u32
    unsigned* h8_dir = h8_ing + (size_t)N_ING * 16;           // N_DIR*16
    __half* s_ing = (__half*)(h8_dir + (size_t)N_DIR * 16);   // N_ING*12 fp16
    __half* s_dir = s_ing + (size_t)N_ING * 12;               // N_DIR*28 fp16
    int*   perm  = (int*)(s_dir + (size_t)N_DIR * 28);        // 5M
    int*   blockcnt  = perm + (size_t)5 * NE;                 // 80*4688
    int*   blockbase = blockcnt + (size_t)NBK * NBUCK;        // 80*4688
    int*   bbase  = blockbase + (size_t)NBK * NBUCK;          // 4688
    int*   btot   = bbase + NBUCK;                            // 4688
    int*   start  = btot + NBUCK;                             // 300K
    int*   cnt    = start + NDST_TOTAL;                       // 300K
    int*   cursor = cnt + NDST_TOTAL;                         // 1  (zeroed region)
    float* pool_ing = (float*)(cursor + 1);                   // 64
    float* pool_dir = pool_ing + 64;                          // 4*64
    float* sem_dir  = pool_dir + 256;                         // 4*64
    unsigned* rows8 = bpair;   // bpair is dead after k4: reuse for 200K*16 u32

    // tiny memset: cursor + pools + sem
    hipMemsetAsync(cursor, 0, (1 + 64 + 256 + 256) * sizeof(int), stream);

    // kA: bucket histogram (LDS-only atomics) + fused proj/fp8/fp16-score
    kA_kernel<<<NBK + PB_ING + PB_DIR, 256, 0, stream>>>(
        ei_cooc, ei_used, ei_contains, ei_pairs, ei_follows, blockcnt,
        x_ing, W_pi, b_pi, as_cooc, as_used, ad_contains, h8_ing, s_ing,
        x_dir, W_pd, b_pd, ad_cooc, ad_used, as_contains, as_pairs, ad_pairs,
        as_follows, ad_follows, h8_dir, s_dir);

    // k2: bucket scan -> bases (64 buckets x 4 threads per block)
    k2_kernel<<<(NBUCK + 63) / 64, 256, 0, stream>>>(
        blockcnt, blockbase, bbase, btot, cursor);

    // k3: bucket scatter (LDS cursors, u32 packed)
    k3_kernel<<<NBK, 256, 0, stream>>>(
        ei_cooc, ei_used, ei_contains, ei_pairs, ei_follows, blockbase, bpair);

    // k4: per-bucket counting sort -> perm + start/cnt
    k4_kernel<<<NBUCK, 256, 0, stream>>>(bpair, bbase, btot, perm, start, cnt);

    // agg over all 300K dst segments; writes fp8 rows for the sem pass
    agg_all_kernel<<<2048, 256, 0, stream>>>(
        perm, start, cnt, h8_ing, h8_dir, s_ing, s_dir, rows8,
        pool_ing, pool_dir);

    // sem: MFMA GEMM + tanh column sums over 200K rows (4 types x 50K)
    sem_kernel<<<512, 256, 0, stream>>>(rows8, Wk, bk, sem_dir);

    final_kernel<<<1, 64, 0, stream>>>(
        pool_ing, pool_dir, sem_dir, q, cond, eps,
        W_mu, b_mu, W_lv, b_lv, W_fc3, b_fc3, W_fc2, b_fc2, (float*)d_out);
}

// Round 5
// 508.446 us; speedup vs baseline: 2.1157x; 1.0256x over previous
//
#include <hip/hip_runtime.h>
#include <hip/hip_fp16.h>
#include <math.h>

#define N_ING 100000
#define N_DIR 50000
#define NE    1000000
#define NDST_TOTAL 300000   // 50K(cooc)+50K(used)+100K(contains)+50K(pairs)+50K(follows)
#define NBUCK 4688          // ceil(300000/64): 64 dst nodes per bucket
#define BA    64            // hist/scatter blocks per edge type (R5: 16->64, 4x parallelism)
#define NBK   (5 * BA)      // 320
#define I4PT  (NE / 4)      // int4s per type
#define PB_ING 384
#define PB_DIR 192
#define LOG2E 1.442695041f

typedef float v2f __attribute__((ext_vector_type(2)));
typedef __attribute__((ext_vector_type(8))) short bf16x8;
typedef __attribute__((ext_vector_type(4))) float f32x4;

// ============ kA: bucket histogram (LDS atomics) + fused proj+score ========
// Attention vectors pre-scaled by log2(e) so agg uses bare v_exp_f32 (exp2).
__global__ __launch_bounds__(256) void kA_kernel(
    const int* __restrict__ e0, const int* __restrict__ e1,
    const int* __restrict__ e2, const int* __restrict__ e3,
    const int* __restrict__ e4, int* __restrict__ blockcnt,
    const float* __restrict__ x_ing, const float* __restrict__ W_pi,
    const float* __restrict__ b_pi,
    const float* __restrict__ as_cooc, const float* __restrict__ as_used,
    const float* __restrict__ ad_contains,
    unsigned* __restrict__ h8_ing, __half* __restrict__ s_ing,
    const float* __restrict__ x_dir, const float* __restrict__ W_pd,
    const float* __restrict__ b_pd,
    const float* __restrict__ ad_cooc, const float* __restrict__ ad_used,
    const float* __restrict__ as_contains, const float* __restrict__ as_pairs,
    const float* __restrict__ ad_pairs, const float* __restrict__ as_follows,
    const float* __restrict__ ad_follows,
    unsigned* __restrict__ h8_dir, __half* __restrict__ s_dir)
{
    __shared__ int hist[NBUCK];
    __shared__ float sW[16 * 64];
    __shared__ float sbb[64];
    __shared__ float satt[7 * 64];
    __shared__ float sx[4][16];
    __shared__ float srow[4][64];

    const int bid = blockIdx.x;
    const int tid = threadIdx.x;
    if (bid < NBK) {
        // ---------- bucket histogram, one row per block ----------
        const int type = bid / BA, blk = bid % BA;
        const int* ei = type == 0 ? e0 : type == 1 ? e1 : type == 2 ? e2
                      : type == 3 ? e3 : e4;
        const int base = type == 0 ? 0 : type == 1 ? 50000 : type == 2 ? 100000
                       : type == 3 ? 200000 : 250000;
        for (int i = tid; i < NBUCK; i += 256) hist[i] = 0;
        __syncthreads();
        const int4* d4 = (const int4*)(ei + NE);
        for (int i = blk * 256 + tid; i < I4PT; i += BA * 256) {
            int4 d = d4[i];
            atomicAdd(&hist[(base + d.x) >> 6], 1);
            atomicAdd(&hist[(base + d.y) >> 6], 1);
            atomicAdd(&hist[(base + d.z) >> 6], 1);
            atomicAdd(&hist[(base + d.w) >> 6], 1);
        }
        __syncthreads();
        int* row = blockcnt + (size_t)bid * NBUCK;
        for (int i = tid; i < NBUCK; i += 256) row[i] = hist[i];
    } else if (bid < NBK + PB_ING) {
        // ---------- proj + fp8 pack + fp16 scores, ingredient nodes ---------
        const int g = tid >> 6, t = tid & 63;
        for (int i = tid; i < 16 * 64; i += 256) sW[i] = W_pi[i];
        if (tid < 64) {
            sbb[tid] = b_pi[tid];
            satt[tid]       = as_cooc[tid] * LOG2E;
            satt[64 + tid]  = as_used[tid] * LOG2E;
            satt[128 + tid] = ad_contains[tid] * LOG2E;
        }
        __syncthreads();
        for (int q = bid - NBK; q < N_ING / 4; q += PB_ING) {
            int n = q * 4 + g;
            if (t < 16) sx[g][t] = x_ing[(size_t)n * 16 + t];
            __syncthreads();
            float s = sbb[t];
#pragma unroll
            for (int i = 0; i < 16; ++i) s += sx[g][i] * sW[i * 64 + t];
            srow[g][t] = s;
            __syncthreads();
            if (t < 16) {
                int w0 = __builtin_amdgcn_cvt_pk_fp8_f32(srow[g][t * 4], srow[g][t * 4 + 1], 0, false);
                int w  = __builtin_amdgcn_cvt_pk_fp8_f32(srow[g][t * 4 + 2], srow[g][t * 4 + 3], w0, true);
                h8_ing[(size_t)n * 16 + t] = (unsigned)w;
            }
            if (t < 12) {
                int slot = t >> 2, hh = t & 3;
                float sc = 0.f;
#pragma unroll
                for (int d = 0; d < 16; ++d)
                    sc += srow[g][hh * 16 + d] * satt[slot * 64 + hh * 16 + d];
                s_ing[(size_t)n * 12 + t] = __float2half(sc);
            }
            __syncthreads();
        }
    } else {
        // ---------- proj + fp8 pack + fp16 scores, direction nodes ----------
        const int g = tid >> 6, t = tid & 63;
        for (int i = tid; i < 8 * 64; i += 256) sW[i] = W_pd[i];
        if (tid < 64) {
            sbb[tid] = b_pd[tid];
            satt[tid]        = ad_cooc[tid] * LOG2E;
            satt[64  + tid]  = ad_used[tid] * LOG2E;
            satt[128 + tid]  = as_contains[tid] * LOG2E;
            satt[192 + tid]  = as_pairs[tid] * LOG2E;
            satt[256 + tid]  = ad_pairs[tid] * LOG2E;
            satt[320 + tid]  = as_follows[tid] * LOG2E;
            satt[384 + tid]  = ad_follows[tid] * LOG2E;
        }
        __syncthreads();
        for (int q = bid - NBK - PB_ING; q < N_DIR / 4; q += PB_DIR) {
            int n = q * 4 + g;
            if (t < 8) sx[g][t] = x_dir[(size_t)n * 8 + t];
            __syncthreads();
            float s = sbb[t];
#pragma unroll
            for (int i = 0; i < 8; ++i) s += sx[g][i] * sW[i * 64 + t];
            srow[g][t] = s;
            __syncthreads();
            if (t < 16) {
                int w0 = __builtin_amdgcn_cvt_pk_fp8_f32(srow[g][t * 4], srow[g][t * 4 + 1], 0, false);
                int w  = __builtin_amdgcn_cvt_pk_fp8_f32(srow[g][t * 4 + 2], srow[g][t * 4 + 3], w0, true);
                h8_dir[(size_t)n * 16 + t] = (unsigned)w;
            }
            if (t < 28) {
                int slot = t >> 2, hh = t & 3;
                float sc = 0.f;
#pragma unroll
                for (int d = 0; d < 16; ++d)
                    sc += srow[g][hh * 16 + d] * satt[slot * 64 + hh * 16 + d];
                s_dir[(size_t)n * 28 + t] = __float2half(sc);
            }
            __syncthreads();
        }
    }
}

// ============ k2: bucket totals + bases, 64 buckets x 4 threads per block ==
__global__ __launch_bounds__(256) void k2_kernel(
    const int* __restrict__ blockcnt, int* __restrict__ blockbase,
    int* __restrict__ bbase, int* __restrict__ btot, int* __restrict__ cursor)
{
    __shared__ int part[4][64];
    __shared__ int tots[64];
    __shared__ int scn[64];
    __shared__ int bw;
    const int tid = threadIdx.x;
    const int kq = tid >> 6, bl = tid & 63;   // 4 k-quarters x 64 buckets
    const int b = blockIdx.x * 64 + bl;
    const int K = NBK / 4;                    // 80 rows per quarter
    int ps = 0;
    if (b < NBUCK)
        for (int k = kq * K; k < kq * K + K; ++k)
            ps += blockcnt[(size_t)k * NBUCK + b];
    part[kq][bl] = ps;
    __syncthreads();
    if (tid < 64) {
        int t = part[0][tid] + part[1][tid] + part[2][tid] + part[3][tid];
        tots[tid] = t;
        scn[tid] = t;
    }
    __syncthreads();
    for (int off = 1; off < 64; off <<= 1) {
        int v = 0;
        if (tid < 64 && tid >= off) v = scn[tid - off];
        __syncthreads();
        if (tid < 64) scn[tid] += v;
        __syncthreads();
    }
    if (tid == 63) bw = atomicAdd(cursor, scn[63]);
    __syncthreads();
    if (b < NBUCK) {
        int bs = bw + scn[bl] - tots[bl];     // exclusive bucket base
        if (kq == 0) {
            bbase[b] = bs;
            btot[b] = tots[bl];
        }
        int run = bs;
        for (int q = 0; q < kq; ++q) run += part[q][bl];
        for (int k = kq * K; k < kq * K + K; ++k) {
            blockbase[(size_t)k * NBUCK + b] = run;
            run += blockcnt[(size_t)k * NBUCK + b];
        }
    }
}

// ============ k3: bucket scatter (LDS cursors, packed u32 entries) =========
__global__ __launch_bounds__(256) void k3_kernel(
    const int* __restrict__ e0, const int* __restrict__ e1,
    const int* __restrict__ e2, const int* __restrict__ e3,
    const int* __restrict__ e4, const int* __restrict__ blockbase,
    unsigned* __restrict__ bpair)
{
    __shared__ int cur[NBUCK];
    const int bid = blockIdx.x, tid = threadIdx.x;
    const int type = bid / BA, blk = bid % BA;
    const int* ei = type == 0 ? e0 : type == 1 ? e1 : type == 2 ? e2
                  : type == 3 ? e3 : e4;
    const int base = type == 0 ? 0 : type == 1 ? 50000 : type == 2 ? 100000
                   : type == 3 ? 200000 : 250000;
    const int* row = blockbase + (size_t)bid * NBUCK;
    for (int i = tid; i < NBUCK; i += 256) cur[i] = row[i];
    __syncthreads();
    const int4* s4 = (const int4*)ei;
    const int4* d4 = (const int4*)(ei + NE);
    for (int i = blk * 256 + tid; i < I4PT; i += BA * 256) {
        int4 s = s4[i];
        int4 d = d4[i];
        int g0 = base + d.x, g1 = base + d.y, g2 = base + d.z, g3 = base + d.w;
        int p0 = atomicAdd(&cur[g0 >> 6], 1);
        int p1 = atomicAdd(&cur[g1 >> 6], 1);
        int p2 = atomicAdd(&cur[g2 >> 6], 1);
        int p3 = atomicAdd(&cur[g3 >> 6], 1);
        bpair[p0] = ((unsigned)(g0 & 63) << 17) | (unsigned)s.x;
        bpair[p1] = ((unsigned)(g1 & 63) << 17) | (unsigned)s.y;
        bpair[p2] = ((unsigned)(g2 & 63) << 17) | (unsigned)s.z;
        bpair[p3] = ((unsigned)(g3 & 63) << 17) | (unsigned)s.w;
    }
}

// ============ k4: per-bucket counting sort -> perm + start/cnt =============
__global__ __launch_bounds__(256) void k4_kernel(
    const unsigned* __restrict__ bpair, const int* __restrict__ bbase,
    const int* __restrict__ btot, int* __restrict__ perm,
    int* __restrict__ start, int* __restrict__ cnt)
{
    __shared__ int h[64], sc[64], cu[64];
    const int b = blockIdx.x, tid = threadIdx.x;
    const int jb = bbase[b], n = btot[b];
    if (tid < 64) h[tid] = 0;
    __syncthreads();
    for (int i = tid; i < n; i += 256)
        atomicAdd(&h[bpair[jb + i] >> 17], 1);
    __syncthreads();
    if (tid == 0) {
        int r = 0;
        for (int i = 0; i < 64; ++i) { sc[i] = r; cu[i] = r; r += h[i]; }
    }
    __syncthreads();
    if (tid < 64) {
        int dg = b * 64 + tid;
        if (dg < NDST_TOTAL) {
            start[dg] = jb + sc[tid];
            cnt[dg] = h[tid];
        }
    }
    for (int i = tid; i < n; i += 256) {
        unsigned p = bpair[jb + i];
        int pos = atomicAdd(&cu[p >> 17], 1);
        perm[jb + pos] = (int)(p & 0x1FFFF);
    }
}

// ============ fused aggregation: fp8 rows, fp16 scores, 16 edges/iter ======
// FROZEN from R4 (185us, VGPR 32, VALU-issue-bound) as the control.
__global__ __launch_bounds__(256) void agg_all_kernel(
    const int* __restrict__ perm, const int* __restrict__ start,
    const int* __restrict__ cnttot,
    const unsigned* __restrict__ h8_ing, const unsigned* __restrict__ h8_dir,
    const __half* __restrict__ s_ing, const __half* __restrict__ s_dir,
    unsigned* __restrict__ rows8,
    float* __restrict__ pool_ing, float* __restrict__ pool_dir)
{
    __shared__ __align__(16) float srow[4][64];
    __shared__ float sred[4][64];
    const int t = threadIdx.x & 63, w = threadIdx.x >> 6;
    const int g  = t >> 4;       // edge group 0..3
    const int l4 = t & 15;       // feature quad: 4*l4 .. 4*l4+3
    const int hq = l4 >> 2;      // head of my features

    float p_ing = 0.f;
    float p0 = 0.f, p1 = 0.f, p2 = 0.f, p3 = 0.f;
    const int nwaves = gridDim.x * 4;
    for (int d = blockIdx.x * 4 + w; d < NDST_TOTAL; d += nwaves) {
        int type, ld;
        const __half *ssrc, *sdst;
        const unsigned* hsrc;
        unsigned uss, uds; int soff, doff;
        if (d < 50000)       { type = 0; ld = d;          ssrc = s_ing; uss = 12; soff = 0;  sdst = s_dir; uds = 28; doff = 0;  hsrc = h8_ing; }
        else if (d < 100000) { type = 1; ld = d - 50000;  ssrc = s_ing; uss = 12; soff = 4;  sdst = s_dir; uds = 28; doff = 4;  hsrc = h8_ing; }
        else if (d < 200000) { type = 2; ld = d - 100000; ssrc = s_dir; uss = 28; soff = 8;  sdst = s_ing; uds = 12; doff = 8;  hsrc = h8_dir; }
        else if (d < 250000) { type = 3; ld = d - 200000; ssrc = s_dir; uss = 28; soff = 12; sdst = s_dir; uds = 28; doff = 16; hsrc = h8_dir; }
        else                 { type = 4; ld = d - 250000; ssrc = s_dir; uss = 28; soff = 20; sdst = s_dir; uds = 28; doff = 24; hsrc = h8_dir; }
        float adst = __half2float(sdst[(unsigned)ld * uds + (unsigned)(doff + hq)]);
        const unsigned usoff = (unsigned)(soff + hq);
        int jb = start[d], je = jb + cnttot[d];
        int jl = je - 1;
        float4 acc = make_float4(0.f, 0.f, 0.f, 0.f);
        float dsum = 0.f;
        for (int j = jb; j < je; j += 16) {
            int j0 = j + g, j1 = j + 4 + g, j2 = j + 8 + g, j3 = j + 12 + g;
            bool v0 = j0 < je, v1 = j1 < je, v2 = j2 < je, v3 = j3 < je;
            unsigned s0 = (unsigned)perm[v0 ? j0 : jl];
            unsigned s1 = (unsigned)perm[v1 ? j1 : jl];
            unsigned s2 = (unsigned)perm[v2 ? j2 : jl];
            unsigned s3 = (unsigned)perm[v3 ? j3 : jl];
            float c0 = __half2float(ssrc[s0 * uss + usoff]);
            float c1 = __half2float(ssrc[s1 * uss + usoff]);
            float c2 = __half2float(ssrc[s2 * uss + usoff]);
            float c3 = __half2float(ssrc[s3 * uss + usoff]);
            unsigned u0 = hsrc[s0 * 16u + (unsigned)l4];
            unsigned u1 = hsrc[s1 * 16u + (unsigned)l4];
            unsigned u2 = hsrc[s2 * 16u + (unsigned)l4];
            unsigned u3 = hsrc[s3 * 16u + (unsigned)l4];
            float a0 = c0 + adst; a0 = a0 > 0.f ? a0 : 0.2f * a0;
            float a1 = c1 + adst; a1 = a1 > 0.f ? a1 : 0.2f * a1;
            float a2 = c2 + adst; a2 = a2 > 0.f ? a2 : 0.2f * a2;
            float a3 = c3 + adst; a3 = a3 > 0.f ? a3 : 0.2f * a3;
            float e0 = v0 ? __builtin_amdgcn_exp2f(a0) : 0.f;  // scores pre-scaled by log2e
            float e1 = v1 ? __builtin_amdgcn_exp2f(a1) : 0.f;
            float e2 = v2 ? __builtin_amdgcn_exp2f(a2) : 0.f;
            float e3 = v3 ? __builtin_amdgcn_exp2f(a3) : 0.f;
            dsum += (e0 + e1) + (e2 + e3);
            v2f lo0 = __builtin_amdgcn_cvt_pk_f32_fp8((int)u0, false);
            v2f hi0 = __builtin_amdgcn_cvt_pk_f32_fp8((int)u0, true);
            v2f lo1 = __builtin_amdgcn_cvt_pk_f32_fp8((int)u1, false);
            v2f hi1 = __builtin_amdgcn_cvt_pk_f32_fp8((int)u1, true);
            v2f lo2 = __builtin_amdgcn_cvt_pk_f32_fp8((int)u2, false);
            v2f hi2 = __builtin_amdgcn_cvt_pk_f32_fp8((int)u2, true);
            v2f lo3 = __builtin_amdgcn_cvt_pk_f32_fp8((int)u3, false);
            v2f hi3 = __builtin_amdgcn_cvt_pk_f32_fp8((int)u3, true);
            acc.x += (lo0.x * e0 + lo1.x * e1) + (lo2.x * e2 + lo3.x * e3);
            acc.y += (lo0.y * e0 + lo1.y * e1) + (lo2.y * e2 + lo3.y * e3);
            acc.z += (hi0.x * e0 + hi1.x * e1) + (hi2.x * e2 + hi3.x * e3);
            acc.w += (hi0.y * e0 + hi1.y * e1) + (hi2.y * e2 + hi3.y * e3);
        }
#pragma unroll
        for (int mask = 16; mask <= 32; mask <<= 1) {
            acc.x += __shfl_xor(acc.x, mask, 64);
            acc.y += __shfl_xor(acc.y, mask, 64);
            acc.z += __shfl_xor(acc.z, mask, 64);
            acc.w += __shfl_xor(acc.w, mask, 64);
            dsum  += __shfl_xor(dsum,  mask, 64);
        }
        float inv = 1.f / (dsum + 1e-16f);
        float4 v4 = make_float4(fmaxf(acc.x * inv, 0.f), fmaxf(acc.y * inv, 0.f),
                                fmaxf(acc.z * inv, 0.f), fmaxf(acc.w * inv, 0.f));
        if (g == 0) *(float4*)&srow[w][l4 * 4] = v4;  // rebroadcast layout
        float v = srow[w][t];                          // wave-coherent LDS
        if (type == 2) {
            p_ing += v;
        } else {
            if (type == 0)      p0 += v;
            else if (type == 1) p1 += v;
            else if (type == 3) p2 += v;
            else                p3 += v;
            // write fp8 row for sem_kernel: md in [0, 200000)
            if (g == 0) {
                unsigned md = (unsigned)(d < 100000 ? d : d - 100000);
                int r0 = __builtin_amdgcn_cvt_pk_fp8_f32(v4.x, v4.y, 0, false);
                int r1 = __builtin_amdgcn_cvt_pk_fp8_f32(v4.z, v4.w, r0, true);
                rows8[md * 16u + (unsigned)l4] = (unsigned)r1;
            }
        }
    }
    float vals[5] = { p_ing, p0, p1, p2, p3 };
    float* outs[5] = { pool_ing, pool_dir, pool_dir + 64, pool_dir + 128,
                       pool_dir + 192 };
    for (int i = 0; i < 5; ++i) {
        __syncthreads();
        sred[w][t] = vals[i];
        __syncthreads();
        if (w == 0)
            atomicAdd(&outs[i][t], sred[0][t] + sred[1][t] + sred[2][t] + sred[3][t]);
    }
}

// ============ sem: MFMA GEMM tanh(R.Wk+bk) column-sums per type ============
__global__ __launch_bounds__(256) void sem_kernel(
    const unsigned* __restrict__ rows8, const float* __restrict__ Wk,
    const float* __restrict__ bk, float* __restrict__ sem_dir)
{
    __shared__ float swk[4096];
    __shared__ float ssem[256];
    const int tid = threadIdx.x;
    for (int i = tid; i < 4096; i += 256) swk[i] = Wk[i];
    ssem[tid] = 0.f;
    __syncthreads();

    const int lane = tid & 63, w = tid >> 6;
    const int col = lane & 15, kg = lane >> 4;

    // B fragments (shared by all tiles): bfr[nt][ks], k = ks*32 + kg*8 + j
    bf16x8 bfr[4][2];
    float biasv[4];
#pragma unroll
    for (int nt = 0; nt < 4; ++nt) {
        biasv[nt] = bk[nt * 16 + col];
#pragma unroll
        for (int ks = 0; ks < 2; ++ks) {
            bf16x8 bb;
#pragma unroll
            for (int j = 0; j < 8; ++j) {
                int k = ks * 32 + kg * 8 + j;
                unsigned u = __builtin_bit_cast(unsigned, swk[k * 64 + nt * 16 + col]);
                u = u + 0x7FFFu + ((u >> 16) & 1u);   // round-to-nearest-even
                bb[j] = (short)(u >> 16);
            }
            bfr[nt][ks] = bb;
        }
    }

    const int gw = blockIdx.x * 4 + w;
    const int nw = gridDim.x * 4;
    for (int tile = gw; tile < 12500; tile += nw) {
        const int tt = tile / 3125;                 // type slot 0..3
        const unsigned* rp = rows8 + (unsigned)(tile * 16 + col) * 16u;
        // A fragments: row = col(=lane&15), k = ks*32 + kg*8 + j
        bf16x8 afr[2];
#pragma unroll
        for (int ks = 0; ks < 2; ++ks) {
            uint2 uu = *(const uint2*)(rp + ks * 8 + kg * 2);
            v2f l0 = __builtin_amdgcn_cvt_pk_f32_fp8((int)uu.x, false);
            v2f h0 = __builtin_amdgcn_cvt_pk_f32_fp8((int)uu.x, true);
            v2f l1 = __builtin_amdgcn_cvt_pk_f32_fp8((int)uu.y, false);
            v2f h1 = __builtin_amdgcn_cvt_pk_f32_fp8((int)uu.y, true);
            bf16x8 aa;   // fp8 values are exactly representable in bf16: truncate
            aa[0] = (short)(__builtin_bit_cast(unsigned, l0.x) >> 16);
            aa[1] = (short)(__builtin_bit_cast(unsigned, l0.y) >> 16);
            aa[2] = (short)(__builtin_bit_cast(unsigned, h0.x) >> 16);
            aa[3] = (short)(__builtin_bit_cast(unsigned, h0.y) >> 16);
            aa[4] = (short)(__builtin_bit_cast(unsigned, l1.x) >> 16);
            aa[5] = (short)(__builtin_bit_cast(unsigned, l1.y) >> 16);
            aa[6] = (short)(__builtin_bit_cast(unsigned, h1.x) >> 16);
            aa[7] = (short)(__builtin_bit_cast(unsigned, h1.y) >> 16);
            afr[ks] = aa;
        }
#pragma unroll
        for (int nt = 0; nt < 4; ++nt) {
            f32x4 acc = {0.f, 0.f, 0.f, 0.f};
            acc = __builtin_amdgcn_mfma_f32_16x16x32_bf16(afr[0], bfr[nt][0], acc, 0, 0, 0);
            acc = __builtin_amdgcn_mfma_f32_16x16x32_bf16(afr[1], bfr[nt][1], acc, 0, 0, 0);
            float s = 0.f;
#pragma unroll
            for (int reg = 0; reg < 4; ++reg) {
                float x = acc[reg] + biasv[nt];
                x = fminf(fmaxf(x, -15.f), 15.f);
                float e = __builtin_amdgcn_exp2f(x * (2.f * LOG2E));
                s += (e - 1.f) * __builtin_amdgcn_rcpf(e + 1.f);
            }
            s += __shfl_xor(s, 16, 64);
            s += __shfl_xor(s, 32, 64);
            if (lane < 16) atomicAdd(&ssem[tt * 64 + nt * 16 + col], s);
        }
    }
    __syncthreads();
    atomicAdd(&sem_dir[tid], ssem[tid]);
}

// ============ final: semantic softmax + pools + VAE head ===================
__global__ __launch_bounds__(64) void final_kernel(
    const float* __restrict__ pool_ing, const float* __restrict__ pool_dir,
    const float* __restrict__ sem_dir, const float* __restrict__ q,
    const float* __restrict__ cond, const float* __restrict__ eps,
    const float* __restrict__ W_mu, const float* __restrict__ b_mu,
    const float* __restrict__ W_lv, const float* __restrict__ b_lv,
    const float* __restrict__ W_fc3, const float* __restrict__ b_fc3,
    const float* __restrict__ W_fc2, const float* __restrict__ b_fc2,
    float* __restrict__ out)
{
    __shared__ float gr[136];
    __shared__ float sc[4], attn[4];
    __shared__ float z[32], hfc[64];
    int t = threadIdx.x;  // 64 threads
    if (t < 4) {
        float s = 0.f;
        for (int f = 0; f < 64; ++f)
            s += (sem_dir[t * 64 + f] / (float)N_DIR) * q[f];
        sc[t] = s;
    }
    gr[t] = pool_ing[t] / (float)N_ING;   // out_ing == o_cont (T=1 softmax)
    __syncthreads();
    if (t == 0) {
        float m = fmaxf(fmaxf(sc[0], sc[1]), fmaxf(sc[2], sc[3]));
        float ssum = 0.f;
        for (int i = 0; i < 4; ++i) { attn[i] = expf(sc[i] - m); ssum += attn[i]; }
        for (int i = 0; i < 4; ++i) attn[i] /= ssum;
    }
    __syncthreads();
    {
        float v = 0.f;
        for (int tt = 0; tt < 4; ++tt)
            v += attn[tt] * (pool_dir[tt * 64 + t] / (float)N_DIR);
        gr[64 + t] = v;
    }
    if (t < 8) gr[128 + t] = cond[t];
    __syncthreads();
    if (t < 32) {
        float m = b_mu[t], lv = b_lv[t];
        for (int i = 0; i < 136; ++i) {
            float g = gr[i];
            m  += g * W_mu[i * 32 + t];
            lv += g * W_lv[i * 32 + t];
        }
        out[16 + t] = m;
        out[48 + t] = lv;
        z[t] = m + eps[t] * expf(0.5f * lv);
    }
    __syncthreads();
    {
        float v = b_fc3[t];
        for (int j = 0; j < 32; ++j) v += z[j] * W_fc3[j * 64 + t];
        hfc[t] = fmaxf(v, 0.f);
    }
    __syncthreads();
    if (t < 16) {
        float v = b_fc2[t];
        for (int f = 0; f < 64; ++f) v += hfc[f] * W_fc2[f * 16 + t];
        out[t] = tanhf(v);
    }
}

extern "C" void kernel_launch(void* const* d_in, const int* in_sizes, int n_in,
                              void* d_out, int out_size, void* d_ws, size_t ws_size,
                              hipStream_t stream) {
    const float* x_ing = (const float*)d_in[0];
    const float* x_dir = (const float*)d_in[1];
    const float* cond  = (const float*)d_in[2];
    const float* eps   = (const float*)d_in[3];
    const int* ei_cooc     = (const int*)d_in[4];
    const int* ei_used     = (const int*)d_in[5];
    const int* ei_contains = (const int*)d_in[6];
    const int* ei_pairs    = (const int*)d_in[7];
    const int* ei_follows  = (const int*)d_in[8];
    const float* W_pi = (const float*)d_in[9];
    const float* b_pi = (const float*)d_in[10];
    const float* W_pd = (const float*)d_in[11];
    const float* b_pd = (const float*)d_in[12];
    const float* Wk   = (const float*)d_in[13];
    const float* bk   = (const float*)d_in[14];
    const float* q    = (const float*)d_in[15];
    const float* W_mu = (const float*)d_in[16];
    const float* b_mu = (const float*)d_in[17];
    const float* W_lv = (const float*)d_in[18];
    const float* b_lv = (const float*)d_in[19];
    const float* W_fc3 = (const float*)d_in[20];
    const float* b_fc3 = (const float*)d_in[21];
    const float* W_fc2 = (const float*)d_in[22];
    const float* b_fc2 = (const float*)d_in[23];
    const float* as_cooc     = (const float*)d_in[24];
    const float* ad_cooc     = (const float*)d_in[25];
    const float* as_used     = (const float*)d_in[26];
    const float* ad_used     = (const float*)d_in[27];
    const float* as_contains = (const float*)d_in[28];
    const float* ad_contains = (const float*)d_in[29];
    const float* as_pairs    = (const float*)d_in[30];
    const float* ad_pairs    = (const float*)d_in[31];
    const float* as_follows  = (const float*)d_in[32];
    const float* ad_follows  = (const float*)d_in[33];

    // ---- workspace layout (time-multiplexed aliases, no net growth) ----
    // Timeline: kA writes blockcnt -> k2 reads blockcnt, writes blockbase ->
    // k3 reads blockbase, writes bpair (kills blockcnt) -> k4 reads bpair,
    // writes perm (kills blockbase) -> agg reads perm, writes rows8 (bpair
    // region, bpair dead) -> sem reads rows8.
    unsigned* bpair = (unsigned*)d_ws;                        // 5M u32 (20 MB)
    unsigned* h8_ing = bpair + (size_t)5 * NE;                // N_ING*16 u32
    unsigned* h8_dir = h8_ing + (size_t)N_ING * 16;           // N_DIR*16
    __half* s_ing = (__half*)(h8_dir + (size_t)N_DIR * 16);   // N_ING*12 fp16
    __half* s_dir = s_ing + (size_t)N_ING * 12;               // N_DIR*28 fp16
    int*   perm  = (int*)(s_dir + (size_t)N_DIR * 28);        // 5M
    int*   bbase  = perm + (size_t)5 * NE;                    // 4688
    int*   btot   = bbase + NBUCK;                            // 4688
    int*   start  = btot + NBUCK;                             // 300K
    int*   cnt    = start + NDST_TOTAL;                       // 300K
    int*   cursor = cnt + NDST_TOTAL;                         // 1  (zeroed region)
    float* pool_ing = (float*)(cursor + 1);                   // 64
    float* pool_dir = pool_ing + 64;                          // 4*64
    float* sem_dir  = pool_dir + 256;                         // 4*64
    unsigned* rows8 = bpair;          // alias: 200K*16 u32 (12.8 MB), post-k4
    int* blockcnt  = (int*)bpair;     // alias: NBK*NBUCK (6 MB), dead before k3
    int* blockbase = (int*)perm;      // alias: NBK*NBUCK (6 MB), dead before k4

    // tiny memset: cursor + pools + sem
    hipMemsetAsync(cursor, 0, (1 + 64 + 256 + 256) * sizeof(int), stream);

    // kA: bucket histogram (LDS-only atomics) + fused proj/fp8/fp16-score
    kA_kernel<<<NBK + PB_ING + PB_DIR, 256, 0, stream>>>(
        ei_cooc, ei_used, ei_contains, ei_pairs, ei_follows, blockcnt,
        x_ing, W_pi, b_pi, as_cooc, as_used, ad_contains, h8_ing, s_ing,
        x_dir, W_pd, b_pd, ad_cooc, ad_used, as_contains, as_pairs, ad_pairs,
        as_follows, ad_follows, h8_dir, s_dir);

    // k2: bucket scan -> bases (64 buckets x 4 threads per block)
    k2_kernel<<<(NBUCK + 63) / 64, 256, 0, stream>>>(
        blockcnt, blockbase, bbase, btot, cursor);

    // k3: bucket scatter (LDS cursors, u32 packed), 320 blocks
    k3_kernel<<<NBK, 256, 0, stream>>>(
        ei_cooc, ei_used, ei_contains, ei_pairs, ei_follows, blockbase, bpair);

    // k4: per-bucket counting sort -> perm + start/cnt
    k4_kernel<<<NBUCK, 256, 0, stream>>>(bpair, bbase, btot, perm, start, cnt);

    // agg over all 300K dst segments; writes fp8 rows for the sem pass
    agg_all_kernel<<<2048, 256, 0, stream>>>(
        perm, start, cnt, h8_ing, h8_dir, s_ing, s_dir, rows8,
        pool_ing, pool_dir);

    // sem: MFMA GEMM + tanh column sums over 200K rows (4 types x 50K)
    sem_kernel<<<512, 256, 0, stream>>>(rows8, Wk, bk, sem_dir);

    final_kernel<<<1, 64, 0, stream>>>(
        pool_ing, pool_dir, sem_dir, q, cond, eps,
        W_mu, b_mu, W_lv, b_lv, W_fc3, b_fc3, W_fc2, b_fc2, (float*)d_out);
}